// Round 1
// baseline (2168.390 us; speedup 1.0000x reference)
//
#include <hip/hip_runtime.h>
#include <math.h>

#define SEQ 4096
#define DMODEL 512
#define NHEAD 8
#define DHEAD 64

// C[M,N] = A[M,K] @ B[K,N] + bias[N]; all row-major fp32.
// 64x64 block tile, BK=16, 256 threads, 4x4 micro-tile per thread.
__global__ __launch_bounds__(256) void gemm_bias(const float* __restrict__ A,
                                                 const float* __restrict__ B,
                                                 const float* __restrict__ bias,
                                                 float* __restrict__ C,
                                                 int M, int N, int K) {
    __shared__ float As[64][17];
    __shared__ float Bs[16][65];
    const int tid = threadIdx.x;
    const int tx = tid % 16;          // output col group
    const int ty = tid / 16;          // output row group
    const int row0 = blockIdx.y * 64;
    const int col0 = blockIdx.x * 64;

    float acc[4][4] = {};

    for (int k0 = 0; k0 < K; k0 += 16) {
        // Load A tile 64x16 (1024 elems, 4 per thread)
#pragma unroll
        for (int i = 0; i < 4; i++) {
            int idx = tid + i * 256;
            int r = idx >> 4, c = idx & 15;
            As[r][c] = A[(size_t)(row0 + r) * K + (k0 + c)];
        }
        // Load B tile 16x64
#pragma unroll
        for (int i = 0; i < 4; i++) {
            int idx = tid + i * 256;
            int r = idx >> 6, c = idx & 63;
            Bs[r][c] = B[(size_t)(k0 + r) * N + (col0 + c)];
        }
        __syncthreads();
#pragma unroll
        for (int k = 0; k < 16; k++) {
            float a[4], b[4];
#pragma unroll
            for (int i = 0; i < 4; i++) a[i] = As[ty * 4 + i][k];
#pragma unroll
            for (int j = 0; j < 4; j++) b[j] = Bs[k][tx * 4 + j];
#pragma unroll
            for (int i = 0; i < 4; i++)
#pragma unroll
                for (int j = 0; j < 4; j++)
                    acc[i][j] += a[i] * b[j];
        }
        __syncthreads();
    }

#pragma unroll
    for (int i = 0; i < 4; i++) {
        int r = row0 + ty * 4 + i;
#pragma unroll
        for (int j = 0; j < 4; j++) {
            int c = col0 + tx * 4 + j;
            C[(size_t)r * N + c] = acc[i][j] + bias[c];
        }
    }
}

// Flash-style causal attention over packed qkv [SEQ][3*DMODEL].
// Block = 256 threads, handles one head (blockIdx.y) and one 64-row Q tile
// (blockIdx.x). Thread (r = tid/4, g = tid%4) owns Q row r and the 16-wide
// slice [g*16, g*16+16) of both score-columns and head-dims.
__global__ __launch_bounds__(256) void attn_kernel(const float* __restrict__ qkv,
                                                   float* __restrict__ out) {
    __shared__ float Qs[64][65];
    __shared__ float Ks[64][65];
    __shared__ float Vs[64][65];
    __shared__ float Ps[64][65];

    const int tid = threadIdx.x;
    const int r = tid >> 2;   // q row within tile (0..63)
    const int g = tid & 3;    // 16-wide group (0..3)
    const int qt = blockIdx.x;
    const int h  = blockIdx.y;
    const int q0 = qt * 64;
    const float scale = 0.125f;   // 1/sqrt(64)

    // Load Q tile: thread loads its 16 contiguous floats of its row.
    {
        const float* qbase = qkv + (size_t)(q0 + r) * (3 * DMODEL) + h * DHEAD + g * 16;
#pragma unroll
        for (int j = 0; j < 16; j += 4) {
            float4 t = *(const float4*)(qbase + j);
            Qs[r][g * 16 + j + 0] = t.x;
            Qs[r][g * 16 + j + 1] = t.y;
            Qs[r][g * 16 + j + 2] = t.z;
            Qs[r][g * 16 + j + 3] = t.w;
        }
    }

    float m = -INFINITY, l = 0.0f;
    float o[16];
#pragma unroll
    for (int j = 0; j < 16; j++) o[j] = 0.0f;

    for (int jt = 0; jt <= qt; jt++) {
        const int k0 = jt * 64;
        __syncthreads();   // protect Ks/Vs/Ps from prior iteration readers; makes Qs visible on iter 0
        {
            const float* kbase = qkv + (size_t)(k0 + r) * (3 * DMODEL) + DMODEL + h * DHEAD + g * 16;
            const float* vbase = qkv + (size_t)(k0 + r) * (3 * DMODEL) + 2 * DMODEL + h * DHEAD + g * 16;
#pragma unroll
            for (int j = 0; j < 16; j += 4) {
                float4 t = *(const float4*)(kbase + j);
                Ks[r][g * 16 + j + 0] = t.x;
                Ks[r][g * 16 + j + 1] = t.y;
                Ks[r][g * 16 + j + 2] = t.z;
                Ks[r][g * 16 + j + 3] = t.w;
                float4 u = *(const float4*)(vbase + j);
                Vs[r][g * 16 + j + 0] = u.x;
                Vs[r][g * 16 + j + 1] = u.y;
                Vs[r][g * 16 + j + 2] = u.z;
                Vs[r][g * 16 + j + 3] = u.w;
            }
        }
        __syncthreads();

        // Scores: this thread computes cols [g*16, g*16+16) of its row.
        float s[16];
#pragma unroll
        for (int c = 0; c < 16; c++) {
            const int kc = g * 16 + c;
            float acc = 0.0f;
#pragma unroll
            for (int d = 0; d < 64; d++)
                acc += Qs[r][d] * Ks[kc][d];
            acc *= scale;
            if (k0 + kc > q0 + r) acc = -INFINITY;   // causal mask
            s[c] = acc;
        }

        // Row max across 16 local + 4 lanes (lanes of a row are consecutive).
        float mt = s[0];
#pragma unroll
        for (int c = 1; c < 16; c++) mt = fmaxf(mt, s[c]);
        mt = fmaxf(mt, __shfl_xor(mt, 1));
        mt = fmaxf(mt, __shfl_xor(mt, 2));

        const float m_new = fmaxf(m, mt);            // finite for every visited tile
        const float alpha = __expf(m - m_new);       // 0 on first tile (m = -inf)

        float lt = 0.0f;
#pragma unroll
        for (int c = 0; c < 16; c++) {
            float p = __expf(s[c] - m_new);          // masked: exp(-inf) = 0
            Ps[r][g * 16 + c] = p;
            lt += p;
        }
        lt += __shfl_xor(lt, 1);
        lt += __shfl_xor(lt, 2);

        l = l * alpha + lt;
        m = m_new;
#pragma unroll
        for (int j = 0; j < 16; j++) o[j] *= alpha;

        __syncthreads();   // Ps visible to the whole row group

        // O[r][g*16+j] += sum_c P[r][c] * V[c][g*16+j]
        for (int c = 0; c < 64; c++) {
            const float pv = Ps[r][c];
#pragma unroll
            for (int j = 0; j < 16; j++)
                o[j] += pv * Vs[c][g * 16 + j];
        }
    }

    const float inv = 1.0f / l;
    float* obase = out + (size_t)(q0 + r) * DMODEL + h * DHEAD + g * 16;
#pragma unroll
    for (int j = 0; j < 16; j++)
        obase[j] = o[j] * inv;
}

extern "C" void kernel_launch(void* const* d_in, const int* in_sizes, int n_in,
                              void* d_out, int out_size, void* d_ws, size_t ws_size,
                              hipStream_t stream) {
    const float* x     = (const float*)d_in[0];
    const float* W_in  = (const float*)d_in[1];
    const float* b_in  = (const float*)d_in[2];
    const float* W_out = (const float*)d_in[3];
    const float* b_out = (const float*)d_in[4];
    // d_in[5] = causal_mask (always 1) — handled unconditionally.
    float* out = (float*)d_out;

    float* qkv      = (float*)d_ws;                         // [SEQ][3*DMODEL]
    float* attn_out = qkv + (size_t)SEQ * 3 * DMODEL;       // [SEQ][DMODEL]

    // 1) qkv = x @ W_in + b_in    (M=4096, N=1536, K=512)
    gemm_bias<<<dim3((3 * DMODEL) / 64, SEQ / 64), 256, 0, stream>>>(
        x, W_in, b_in, qkv, SEQ, 3 * DMODEL, DMODEL);

    // 2) causal flash attention per (head, q-tile)
    attn_kernel<<<dim3(SEQ / 64, NHEAD), 256, 0, stream>>>(qkv, attn_out);

    // 3) out = attn_out @ W_out + b_out   (M=4096, N=512, K=512)
    gemm_bias<<<dim3(DMODEL / 64, SEQ / 64), 256, 0, stream>>>(
        attn_out, W_out, b_out, out, SEQ, DMODEL, DMODEL);
}

// Round 2
// 391.425 us; speedup vs baseline: 5.5397x; 5.5397x over previous
//
#include <hip/hip_runtime.h>
#include <math.h>

#define SEQ 4096
#define DM 512
#define NH 8
#define DH 64
#define TQK (3 * DM)   // 1536

typedef __attribute__((ext_vector_type(8))) short bf16x8;
typedef __attribute__((ext_vector_type(4))) float floatx4;

__device__ __forceinline__ floatx4 mfma16(bf16x8 a, bf16x8 b, floatx4 c) {
    return __builtin_amdgcn_mfma_f32_16x16x32_bf16(a, b, c, 0, 0, 0);
}

// fp32 -> bf16 round-to-nearest-even
__device__ __forceinline__ unsigned int pk2(float a, float b) {
    unsigned int ua = __float_as_uint(a); ua = (ua + 0x7FFFu + ((ua >> 16) & 1u)) >> 16;
    unsigned int ub = __float_as_uint(b); ub = (ub + 0x7FFFu + ((ub >> 16) & 1u)) >> 16;
    return ua | (ub << 16);
}
__device__ __forceinline__ unsigned short f2bf(float x) {
    unsigned int u = __float_as_uint(x);
    return (unsigned short)((u + 0x7FFFu + ((u >> 16) & 1u)) >> 16);
}

// ---------------- fp32 GEMM + bias (unchanged from round 1) ----------------
__global__ __launch_bounds__(256) void gemm_bias(const float* __restrict__ A,
                                                 const float* __restrict__ B,
                                                 const float* __restrict__ bias,
                                                 float* __restrict__ C,
                                                 int M, int N, int K) {
    __shared__ float As[64][17];
    __shared__ float Bs[16][65];
    const int tid = threadIdx.x;
    const int tx = tid % 16;
    const int ty = tid / 16;
    const int row0 = blockIdx.y * 64;
    const int col0 = blockIdx.x * 64;

    float acc[4][4] = {};

    for (int k0 = 0; k0 < K; k0 += 16) {
#pragma unroll
        for (int i = 0; i < 4; i++) {
            int idx = tid + i * 256;
            int r = idx >> 4, c = idx & 15;
            As[r][c] = A[(size_t)(row0 + r) * K + (k0 + c)];
        }
#pragma unroll
        for (int i = 0; i < 4; i++) {
            int idx = tid + i * 256;
            int r = idx >> 6, c = idx & 63;
            Bs[r][c] = B[(size_t)(k0 + r) * N + (col0 + c)];
        }
        __syncthreads();
#pragma unroll
        for (int k = 0; k < 16; k++) {
            float a[4], b[4];
#pragma unroll
            for (int i = 0; i < 4; i++) a[i] = As[ty * 4 + i][k];
#pragma unroll
            for (int j = 0; j < 4; j++) b[j] = Bs[k][tx * 4 + j];
#pragma unroll
            for (int i = 0; i < 4; i++)
#pragma unroll
                for (int j = 0; j < 4; j++)
                    acc[i][j] += a[i] * b[j];
        }
        __syncthreads();
    }

#pragma unroll
    for (int i = 0; i < 4; i++) {
        int r = row0 + ty * 4 + i;
#pragma unroll
        for (int j = 0; j < 4; j++) {
            int c = col0 + tx * 4 + j;
            C[(size_t)r * N + c] = acc[i][j] + bias[c];
        }
    }
}

// ---------------- V transpose: qkv fp32 V-part -> bf16 [h][d][seq] ----------------
__global__ __launch_bounds__(256) void v_transpose(const float* __restrict__ qkv,
                                                   unsigned short* __restrict__ vt) {
    __shared__ float T[64][65];   // [dim][key], pitch 65 -> 2-way-free banks
    const int tid = threadIdx.x;
    const int s0 = blockIdx.x * 64;
    const int h  = blockIdx.y;
    const int r = tid >> 2, g = tid & 3;

    const float* vb = qkv + (size_t)(s0 + r) * TQK + 2 * DM + h * DH + g * 16;
    float v[16];
#pragma unroll
    for (int i = 0; i < 4; i++) {
        float4 f = ((const float4*)vb)[i];
        v[i * 4 + 0] = f.x; v[i * 4 + 1] = f.y; v[i * 4 + 2] = f.z; v[i * 4 + 3] = f.w;
    }
#pragma unroll
    for (int j = 0; j < 16; j++) T[g * 16 + j][r] = v[j];
    __syncthreads();

    const int d = tid >> 2, g2 = tid & 3;
    unsigned int pk[8];
#pragma unroll
    for (int j = 0; j < 8; j++)
        pk[j] = pk2(T[d][g2 * 16 + 2 * j], T[d][g2 * 16 + 2 * j + 1]);
    unsigned short* ob = vt + (size_t)(h * DH + d) * SEQ + s0 + g2 * 16;
    ((uint4*)ob)[0] = make_uint4(pk[0], pk[1], pk[2], pk[3]);
    ((uint4*)ob)[1] = make_uint4(pk[4], pk[5], pk[6], pk[7]);
}

// ---------------- MFMA flash attention ----------------
// Block = 256 threads (4 waves), one 64-row Q tile of one head.
// Wave w owns q-rows [w*16, w*16+16). K-tiles of 64 keys, online softmax.
// LDS tiles bf16, row pitch 72 (144 B): all MFMA frag reads are aligned
// ds_read_b128 with uniform bank spread.
__global__ __launch_bounds__(256) void attn_mfma(const float* __restrict__ qkv,
                                                 const unsigned short* __restrict__ vt,
                                                 float* __restrict__ out) {
    __shared__ __align__(16) unsigned short Qs[64 * 72];
    __shared__ __align__(16) unsigned short Ks[64 * 72];
    __shared__ __align__(16) unsigned short Vs[64 * 72];   // [dim][key]
    __shared__ __align__(16) unsigned short Ps[64 * 72];   // per-wave 16-row slabs

    const int tid  = threadIdx.x;
    const int lane = tid & 63;
    const int w    = tid >> 6;
    const int quad = lane >> 4;
    const int ln   = lane & 15;
    const int h    = blockIdx.y;
    // complementary pairing: blocks b and b+256 (heads h, h+4) get K-ranges
    // summing to 65 tiles -> balanced CUs under round-robin dispatch
    const int qt   = (h & 4) ? (63 - (int)blockIdx.x) : (int)blockIdx.x;
    const int q0   = qt * 64;

    {   // stage Q tile (fp32 -> bf16)
        const int r = tid >> 2, g = tid & 3;
        const float* qb = qkv + (size_t)(q0 + r) * TQK + h * DH + g * 16;
        float4 f0 = ((const float4*)qb)[0];
        float4 f1 = ((const float4*)qb)[1];
        float4 f2 = ((const float4*)qb)[2];
        float4 f3 = ((const float4*)qb)[3];
        uint4* dst = (uint4*)&Qs[r * 72 + g * 16];
        dst[0] = make_uint4(pk2(f0.x, f0.y), pk2(f0.z, f0.w), pk2(f1.x, f1.y), pk2(f1.z, f1.w));
        dst[1] = make_uint4(pk2(f2.x, f2.y), pk2(f2.z, f2.w), pk2(f3.x, f3.y), pk2(f3.z, f3.w));
    }

    float m_r[4], l_r[4];
    floatx4 o[4];
#pragma unroll
    for (int r = 0; r < 4; r++) { m_r[r] = -INFINITY; l_r[r] = 0.f; }
#pragma unroll
    for (int t = 0; t < 4; t++) o[t] = (floatx4){0.f, 0.f, 0.f, 0.f};

    for (int jt = 0; jt <= qt; ++jt) {
        const int k0 = jt * 64;
        __syncthreads();   // protects Qs (iter 0) and Ks/Vs from prior-iter readers
        {   // stage K (fp32->bf16) and V (pre-transposed bf16 copy)
            const int r = tid >> 2, g = tid & 3;
            const float* kb = qkv + (size_t)(k0 + r) * TQK + DM + h * DH + g * 16;
            float4 f0 = ((const float4*)kb)[0];
            float4 f1 = ((const float4*)kb)[1];
            float4 f2 = ((const float4*)kb)[2];
            float4 f3 = ((const float4*)kb)[3];
            uint4* kd = (uint4*)&Ks[r * 72 + g * 16];
            kd[0] = make_uint4(pk2(f0.x, f0.y), pk2(f0.z, f0.w), pk2(f1.x, f1.y), pk2(f1.z, f1.w));
            kd[1] = make_uint4(pk2(f2.x, f2.y), pk2(f2.z, f2.w), pk2(f3.x, f3.y), pk2(f3.z, f3.w));
            const uint4* vb = (const uint4*)(vt + (size_t)(h * DH + r) * SEQ + k0 + g * 16);
            uint4* vd = (uint4*)&Vs[r * 72 + g * 16];
            vd[0] = vb[0];
            vd[1] = vb[1];
        }
        __syncthreads();

        // ---- S = Q K^T : 16x64 per wave, 8 MFMAs ----
        const bf16x8 a0 = *(const bf16x8*)&Qs[(w * 16 + ln) * 72 + quad * 8];
        const bf16x8 a1 = *(const bf16x8*)&Qs[(w * 16 + ln) * 72 + quad * 8 + 32];
        floatx4 sa[4];
#pragma unroll
        for (int t = 0; t < 4; t++) {
            const bf16x8 b0 = *(const bf16x8*)&Ks[(t * 16 + ln) * 72 + quad * 8];
            const bf16x8 b1 = *(const bf16x8*)&Ks[(t * 16 + ln) * 72 + quad * 8 + 32];
            floatx4 acc = {0.f, 0.f, 0.f, 0.f};
            acc = mfma16(a0, b0, acc);
            acc = mfma16(a1, b1, acc);
            sa[t] = acc;
        }

        // C-layout: lane holds rows quad*4+r, col t*16+ln
        float s[4][4];
#pragma unroll
        for (int t = 0; t < 4; t++)
#pragma unroll
            for (int r = 0; r < 4; r++)
                s[t][r] = sa[t][r] * 0.125f;

        if (jt == qt) {   // diagonal tile: causal mask (k0 == q0)
#pragma unroll
            for (int t = 0; t < 4; t++) {
                const int cg = t * 16 + ln;
#pragma unroll
                for (int r = 0; r < 4; r++) {
                    const int rg = w * 16 + quad * 4 + r;
                    if (cg > rg) s[t][r] = -INFINITY;
                }
            }
        }

        // ---- online softmax (row lives in the 16 lanes of one quad) ----
#pragma unroll
        for (int r = 0; r < 4; r++) {
            float mx = fmaxf(fmaxf(s[0][r], s[1][r]), fmaxf(s[2][r], s[3][r]));
            mx = fmaxf(mx, __shfl_xor(mx, 1));
            mx = fmaxf(mx, __shfl_xor(mx, 2));
            mx = fmaxf(mx, __shfl_xor(mx, 4));
            mx = fmaxf(mx, __shfl_xor(mx, 8));
            const float mn = fmaxf(m_r[r], mx);
            const float alpha = __expf(m_r[r] - mn);   // 0 on first tile
            float ls = 0.f;
#pragma unroll
            for (int t = 0; t < 4; t++) {
                const float p = __expf(s[t][r] - mn);
                ls += p;
                Ps[(w * 16 + quad * 4 + r) * 72 + t * 16 + ln] = f2bf(p);
            }
            ls += __shfl_xor(ls, 1);
            ls += __shfl_xor(ls, 2);
            ls += __shfl_xor(ls, 4);
            ls += __shfl_xor(ls, 8);
            l_r[r] = l_r[r] * alpha + ls;
            m_r[r] = mn;
#pragma unroll
            for (int t = 0; t < 4; t++) o[t][r] *= alpha;
        }

        // keep the P ds_writes ordered before the A-frag ds_reads (same wave,
        // in-order DS pipe makes the cross-lane RAW safe)
        __builtin_amdgcn_wave_barrier();

        // ---- O += P V : P A-frags from per-wave LDS slab, V B-frags from Vs[dim][key] ----
        const bf16x8 p0 = *(const bf16x8*)&Ps[(w * 16 + ln) * 72 + quad * 8];
        const bf16x8 p1 = *(const bf16x8*)&Ps[(w * 16 + ln) * 72 + quad * 8 + 32];
#pragma unroll
        for (int t = 0; t < 4; t++) {
            const bf16x8 v0 = *(const bf16x8*)&Vs[(t * 16 + ln) * 72 + quad * 8];
            const bf16x8 v1 = *(const bf16x8*)&Vs[(t * 16 + ln) * 72 + quad * 8 + 32];
            o[t] = mfma16(p0, v0, o[t]);
            o[t] = mfma16(p1, v1, o[t]);
        }
    }

    // epilogue: normalize and store (fp32)
#pragma unroll
    for (int t = 0; t < 4; t++) {
#pragma unroll
        for (int r = 0; r < 4; r++) {
            out[(size_t)(q0 + w * 16 + quad * 4 + r) * DM + h * DH + t * 16 + ln] =
                o[t][r] / l_r[r];
        }
    }
}

extern "C" void kernel_launch(void* const* d_in, const int* in_sizes, int n_in,
                              void* d_out, int out_size, void* d_ws, size_t ws_size,
                              hipStream_t stream) {
    const float* x     = (const float*)d_in[0];
    const float* W_in  = (const float*)d_in[1];
    const float* b_in  = (const float*)d_in[2];
    const float* W_out = (const float*)d_in[3];
    const float* b_out = (const float*)d_in[4];
    float* out = (float*)d_out;

    float* qkv            = (float*)d_ws;                       // 4096 x 1536 fp32
    float* attn_out       = qkv + (size_t)SEQ * TQK;            // 4096 x 512 fp32
    unsigned short* vtb   = (unsigned short*)(attn_out + (size_t)SEQ * DM);  // bf16 [8][64][4096]

    // 1) qkv = x @ W_in + b_in
    gemm_bias<<<dim3(TQK / 64, SEQ / 64), 256, 0, stream>>>(x, W_in, b_in, qkv, SEQ, TQK, DM);

    // 2) V -> bf16 transposed [h][d][seq]
    v_transpose<<<dim3(SEQ / 64, NH), 256, 0, stream>>>(qkv, vtb);

    // 3) causal flash attention (bf16 MFMA)
    attn_mfma<<<dim3(SEQ / 64, NH), 256, 0, stream>>>(qkv, vtb, attn_out);

    // 4) out = attn_out @ W_out + b_out
    gemm_bias<<<dim3(DM / 64, SEQ / 64), 256, 0, stream>>>(attn_out, W_out, b_out, out, SEQ, DM, DM);
}

// Round 3
// 207.069 us; speedup vs baseline: 10.4718x; 1.8903x over previous
//
#include <hip/hip_runtime.h>
#include <math.h>

#define SEQ 4096
#define DM 512
#define NH 8
#define DH 64
#define TQK (3 * DM)   // 1536

typedef __attribute__((ext_vector_type(8))) short bf16x8;
typedef __attribute__((ext_vector_type(4))) float floatx4;
typedef unsigned short ushort_t;

__device__ __forceinline__ floatx4 mfma16(bf16x8 a, bf16x8 b, floatx4 c) {
    return __builtin_amdgcn_mfma_f32_16x16x32_bf16(a, b, c, 0, 0, 0);
}

// fp32 -> bf16 round-to-nearest-even
__device__ __forceinline__ unsigned int pk2(float a, float b) {
    unsigned int ua = __float_as_uint(a); ua = (ua + 0x7FFFu + ((ua >> 16) & 1u)) >> 16;
    unsigned int ub = __float_as_uint(b); ub = (ub + 0x7FFFu + ((ub >> 16) & 1u)) >> 16;
    return ua | (ub << 16);
}
__device__ __forceinline__ unsigned short f2bf(float x) {
    unsigned int u = __float_as_uint(x);
    return (unsigned short)((u + 0x7FFFu + ((u >> 16) & 1u)) >> 16);
}

// async global->LDS, 16 B per lane; LDS dest = wave-uniform base + lane*16
__device__ __forceinline__ void gload_lds16(const void* g, void* l) {
    __builtin_amdgcn_global_load_lds(
        (const __attribute__((address_space(1))) unsigned int*)g,
        (__attribute__((address_space(3))) unsigned int*)l, 16, 0, 0);
}

// ---------------- fp32 -> bf16 bulk convert (8 floats / thread) ----------------
__global__ __launch_bounds__(256) void f2bf_vec(const float* __restrict__ in,
                                                ushort_t* __restrict__ out) {
    const int i = blockIdx.x * 256 + threadIdx.x;
    const float4* p = (const float4*)in + (size_t)i * 2;
    float4 f0 = p[0], f1 = p[1];
    ((uint4*)out)[i] = make_uint4(pk2(f0.x, f0.y), pk2(f0.z, f0.w),
                                  pk2(f1.x, f1.y), pk2(f1.z, f1.w));
}

// ---------------- W [K x N] fp32 -> WT [N x K] bf16 ----------------
__global__ __launch_bounds__(256) void wt_bf16(const float* __restrict__ W,
                                               ushort_t* __restrict__ WT,
                                               int K, int N) {
    __shared__ float T[64][65];   // [n-local][k-local]
    const int tid = threadIdx.x;
    const int k0 = blockIdx.y * 64, n0 = blockIdx.x * 64;
    {
        const int r = tid >> 2, g = tid & 3;
        const float* src = W + (size_t)(k0 + r) * N + n0 + g * 16;
#pragma unroll
        for (int i = 0; i < 4; i++) {
            float4 f = ((const float4*)src)[i];
            T[g * 16 + i * 4 + 0][r] = f.x;
            T[g * 16 + i * 4 + 1][r] = f.y;
            T[g * 16 + i * 4 + 2][r] = f.z;
            T[g * 16 + i * 4 + 3][r] = f.w;
        }
    }
    __syncthreads();
    const int nr = tid >> 2, g2 = tid & 3;
    unsigned int pk[8];
#pragma unroll
    for (int j = 0; j < 8; j++)
        pk[j] = pk2(T[nr][g2 * 16 + 2 * j], T[nr][g2 * 16 + 2 * j + 1]);
    ushort_t* dst = WT + (size_t)(n0 + nr) * K + k0 + g2 * 16;
    ((uint4*)dst)[0] = make_uint4(pk[0], pk[1], pk[2], pk[3]);
    ((uint4*)dst)[1] = make_uint4(pk[4], pk[5], pk[6], pk[7]);
}

// ---------------- bf16 MFMA GEMM:  C = A @ BT^T + bias ----------------
// A [M x K] bf16 row-major, BT [N x K] bf16 row-major.
// 128x128 tile, BK=64, 256 threads (4 waves, 2x2 wave quadrants, 4x4 mfma each).
// LDS layout: row pitch 64 elems, XOR chunk swizzle (chunk j of row r holds
// global chunk j ^ (r&7)) -> global_load_lds-compatible AND conflict-free reads.
template <bool OUT_BF16>
__global__ __launch_bounds__(256) void gemm_mfma(const ushort_t* __restrict__ A,
                                                 const ushort_t* __restrict__ BT,
                                                 const float* __restrict__ bias,
                                                 void* __restrict__ Cv,
                                                 int M, int N, int K) {
    __shared__ __align__(16) ushort_t As[128 * 64];
    __shared__ __align__(16) ushort_t Bs[128 * 64];
    const int tid  = threadIdx.x;
    const int lane = tid & 63;
    const int w    = tid >> 6;
    const int quad = lane >> 4;
    const int ln   = lane & 15;
    const int row0 = blockIdx.y * 128;
    const int col0 = blockIdx.x * 128;
    const int wm = w >> 1, wn = w & 1;

    const int srow = lane >> 3;                       // 0..7 row-in-group
    const int js   = (lane & 7) ^ srow;               // swizzled source chunk

    floatx4 acc[4][4];
#pragma unroll
    for (int i = 0; i < 4; i++)
#pragma unroll
        for (int j = 0; j < 4; j++) acc[i][j] = (floatx4){0.f, 0.f, 0.f, 0.f};

    for (int k0 = 0; k0 < K; k0 += 64) {
        __syncthreads();
#pragma unroll
        for (int i = 0; i < 4; i++) {
            const int c = w * 4 + i;                  // 0..15 -> 8-row group
            gload_lds16(A + (size_t)(row0 + c * 8 + srow) * K + k0 + js * 8, &As[c * 512]);
            gload_lds16(BT + (size_t)(col0 + c * 8 + srow) * K + k0 + js * 8, &Bs[c * 512]);
        }
        __syncthreads();

#pragma unroll
        for (int s = 0; s < 2; s++) {
            bf16x8 af[4], bfr[4];
#pragma unroll
            for (int i = 0; i < 4; i++) {
                const int lm = wm * 64 + i * 16 + ln;
                af[i] = *(const bf16x8*)&As[lm * 64 + ((s * 4 + quad) ^ (ln & 7)) * 8];
                const int lnn = wn * 64 + i * 16 + ln;
                bfr[i] = *(const bf16x8*)&Bs[lnn * 64 + ((s * 4 + quad) ^ (ln & 7)) * 8];
            }
#pragma unroll
            for (int i = 0; i < 4; i++)
#pragma unroll
                for (int j = 0; j < 4; j++)
                    acc[i][j] = mfma16(af[i], bfr[j], acc[i][j]);
        }
    }

#pragma unroll
    for (int j = 0; j < 4; j++) {
        const int n = col0 + wn * 64 + j * 16 + ln;
        const float bv = bias[n];
#pragma unroll
        for (int i = 0; i < 4; i++) {
            const int mb = row0 + wm * 64 + i * 16 + quad * 4;
#pragma unroll
            for (int r = 0; r < 4; r++) {
                const float v = acc[i][j][r] + bv;
                if (OUT_BF16) ((ushort_t*)Cv)[(size_t)(mb + r) * N + n] = f2bf(v);
                else          ((float*)Cv)[(size_t)(mb + r) * N + n] = v;
            }
        }
    }
}

// ---------------- V transpose: bf16 qkv V-part -> bf16 [h][d][seq] ----------------
__global__ __launch_bounds__(256) void v_transpose(const ushort_t* __restrict__ qkv_b,
                                                   ushort_t* __restrict__ vt) {
    __shared__ ushort_t T[64][72];   // [d][s]
    const int tid = threadIdx.x;
    const int s0 = blockIdx.x * 64;
    const int h  = blockIdx.y;
    {
        const int r = tid >> 2, g = tid & 3;
        const ushort_t* src = qkv_b + (size_t)(s0 + r) * TQK + 2 * DM + h * DH + g * 16;
        ushort_t tmp[16];
        *(uint4*)&tmp[0] = ((const uint4*)src)[0];
        *(uint4*)&tmp[8] = ((const uint4*)src)[1];
#pragma unroll
        for (int j = 0; j < 16; j++) T[g * 16 + j][r] = tmp[j];
    }
    __syncthreads();
    const int d = tid >> 2, g2 = tid & 3;
    uint4 a = *(const uint4*)&T[d][g2 * 16];
    uint4 b = *(const uint4*)&T[d][g2 * 16 + 8];
    ushort_t* dst = vt + (size_t)(h * DH + d) * SEQ + s0 + g2 * 16;
    ((uint4*)dst)[0] = a;
    ((uint4*)dst)[1] = b;
}

// ---------------- MFMA flash attention (bf16 in / bf16 out) ----------------
__global__ __launch_bounds__(256) void attn_mfma(const ushort_t* __restrict__ qkv_b,
                                                 const ushort_t* __restrict__ vt,
                                                 ushort_t* __restrict__ attn_out) {
    __shared__ __align__(16) ushort_t Ks[64 * 64];   // swizzled, pitch 64
    __shared__ __align__(16) ushort_t Vs[64 * 64];   // [d][key], swizzled
    __shared__ __align__(16) ushort_t Ps[64 * 72];   // P slab, padded pitch

    const int tid  = threadIdx.x;
    const int lane = tid & 63;
    const int w    = tid >> 6;
    const int quad = lane >> 4;
    const int ln   = lane & 15;
    const int h    = blockIdx.y;
    const int qt   = (h & 4) ? (63 - (int)blockIdx.x) : (int)blockIdx.x;
    const int q0   = qt * 64;

    // Q fragments straight from global (bf16 already)
    const ushort_t* qrow = qkv_b + (size_t)(q0 + w * 16 + ln) * TQK + h * DH;
    const bf16x8 a0 = *(const bf16x8*)(qrow + quad * 8);
    const bf16x8 a1 = *(const bf16x8*)(qrow + quad * 8 + 32);

    float m_r[4], l_r[4];
    floatx4 o[4];
#pragma unroll
    for (int r = 0; r < 4; r++) { m_r[r] = -INFINITY; l_r[r] = 0.f; }
#pragma unroll
    for (int t = 0; t < 4; t++) o[t] = (floatx4){0.f, 0.f, 0.f, 0.f};

    const int srow = lane >> 3;            // 0..7
    const int js   = (lane & 7) ^ srow;    // swizzled source chunk

    for (int jt = 0; jt <= qt; ++jt) {
        const int k0 = jt * 64;
        __syncthreads();   // protect Ks/Vs from prior-iter readers
#pragma unroll
        for (int i = 0; i < 2; i++) {
            const int c = w * 2 + i;       // 8-row group 0..7
            gload_lds16(qkv_b + (size_t)(k0 + c * 8 + srow) * TQK + DM + h * DH + js * 8,
                        &Ks[c * 512]);
            gload_lds16(vt + (size_t)(h * DH + c * 8 + srow) * SEQ + k0 + js * 8,
                        &Vs[c * 512]);
        }
        __syncthreads();

        // ---- S = Q K^T : 16x64 per wave ----
        floatx4 sa[4];
#pragma unroll
        for (int t = 0; t < 4; t++) {
            const int n = t * 16 + ln;
            const bf16x8 b0 = *(const bf16x8*)&Ks[n * 64 + ((quad) ^ (ln & 7)) * 8];
            const bf16x8 b1 = *(const bf16x8*)&Ks[n * 64 + ((4 + quad) ^ (ln & 7)) * 8];
            floatx4 acc = {0.f, 0.f, 0.f, 0.f};
            acc = mfma16(a0, b0, acc);
            acc = mfma16(a1, b1, acc);
            sa[t] = acc;
        }

        float s[4][4];
#pragma unroll
        for (int t = 0; t < 4; t++)
#pragma unroll
            for (int r = 0; r < 4; r++)
                s[t][r] = sa[t][r] * 0.125f;

        if (jt == qt) {   // diagonal tile: causal mask
#pragma unroll
            for (int t = 0; t < 4; t++) {
                const int cg = t * 16 + ln;
#pragma unroll
                for (int r = 0; r < 4; r++) {
                    const int rg = w * 16 + quad * 4 + r;
                    if (cg > rg) s[t][r] = -INFINITY;
                }
            }
        }

        // ---- online softmax (row = 16 lanes of one quad) ----
#pragma unroll
        for (int r = 0; r < 4; r++) {
            float mx = fmaxf(fmaxf(s[0][r], s[1][r]), fmaxf(s[2][r], s[3][r]));
            mx = fmaxf(mx, __shfl_xor(mx, 1));
            mx = fmaxf(mx, __shfl_xor(mx, 2));
            mx = fmaxf(mx, __shfl_xor(mx, 4));
            mx = fmaxf(mx, __shfl_xor(mx, 8));
            const float mn = fmaxf(m_r[r], mx);
            const float alpha = __expf(m_r[r] - mn);
            float ls = 0.f;
#pragma unroll
            for (int t = 0; t < 4; t++) {
                const float p = __expf(s[t][r] - mn);
                ls += p;
                Ps[(w * 16 + quad * 4 + r) * 72 + t * 16 + ln] = f2bf(p);
            }
            ls += __shfl_xor(ls, 1);
            ls += __shfl_xor(ls, 2);
            ls += __shfl_xor(ls, 4);
            ls += __shfl_xor(ls, 8);
            l_r[r] = l_r[r] * alpha + ls;
            m_r[r] = mn;
#pragma unroll
            for (int t = 0; t < 4; t++) o[t][r] *= alpha;
        }

        __builtin_amdgcn_wave_barrier();   // order P writes before A-frag reads

        const bf16x8 p0 = *(const bf16x8*)&Ps[(w * 16 + ln) * 72 + quad * 8];
        const bf16x8 p1 = *(const bf16x8*)&Ps[(w * 16 + ln) * 72 + quad * 8 + 32];
#pragma unroll
        for (int t = 0; t < 4; t++) {
            const int d = t * 16 + ln;
            const bf16x8 v0 = *(const bf16x8*)&Vs[d * 64 + ((quad) ^ (ln & 7)) * 8];
            const bf16x8 v1 = *(const bf16x8*)&Vs[d * 64 + ((4 + quad) ^ (ln & 7)) * 8];
            o[t] = mfma16(p0, v0, o[t]);
            o[t] = mfma16(p1, v1, o[t]);
        }
    }

    // epilogue: normalize, bf16 store
#pragma unroll
    for (int t = 0; t < 4; t++) {
#pragma unroll
        for (int r = 0; r < 4; r++) {
            attn_out[(size_t)(q0 + w * 16 + quad * 4 + r) * DM + h * DH + t * 16 + ln] =
                f2bf(o[t][r] / l_r[r]);
        }
    }
}

extern "C" void kernel_launch(void* const* d_in, const int* in_sizes, int n_in,
                              void* d_out, int out_size, void* d_ws, size_t ws_size,
                              hipStream_t stream) {
    const float* x     = (const float*)d_in[0];
    const float* W_in  = (const float*)d_in[1];
    const float* b_in  = (const float*)d_in[2];
    const float* W_out = (const float*)d_in[3];
    const float* b_out = (const float*)d_in[4];
    float* out = (float*)d_out;

    // workspace layout (bytes)
    char* ws = (char*)d_ws;
    ushort_t* xb    = (ushort_t*)ws;                           //  4 MB  x bf16 [4096][512]
    ushort_t* wti   = (ushort_t*)(ws + (4u << 20));            //  1.5MB W_in^T bf16 [1536][512]
    ushort_t* wto   = (ushort_t*)(ws + (6u << 20));            //  0.5MB W_out^T bf16 [512][512]
    ushort_t* qkv_b = (ushort_t*)(ws + (7u << 20));            // 12 MB  qkv bf16 [4096][1536]
    ushort_t* vtb   = (ushort_t*)(ws + (20u << 20));           //  4 MB  V^T bf16 [8][64][4096]
    ushort_t* aob   = (ushort_t*)(ws + (25u << 20));           //  4 MB  attn out bf16 [4096][512]

    // 0) conversions / transposes
    f2bf_vec<<<(SEQ * DM / 8 + 255) / 256, 256, 0, stream>>>(x, xb);
    wt_bf16<<<dim3(TQK / 64, DM / 64), 256, 0, stream>>>(W_in, wti, DM, TQK);
    wt_bf16<<<dim3(DM / 64, DM / 64), 256, 0, stream>>>(W_out, wto, DM, DM);

    // 1) qkv = x @ W_in + b_in  (bf16 out)
    gemm_mfma<true><<<dim3(TQK / 128, SEQ / 128), 256, 0, stream>>>(
        xb, wti, b_in, qkv_b, SEQ, TQK, DM);

    // 2) V -> [h][d][seq]
    v_transpose<<<dim3(SEQ / 64, NH), 256, 0, stream>>>(qkv_b, vtb);

    // 3) causal flash attention
    attn_mfma<<<dim3(SEQ / 64, NH), 256, 0, stream>>>(qkv_b, vtb, aob);

    // 4) out = attn_out @ W_out + b_out  (fp32 out)
    gemm_mfma<false><<<dim3(DM / 128, SEQ / 128), 256, 0, stream>>>(
        aob, wto, b_out, out, SEQ, DM, DM);
}

// Round 4
// 188.243 us; speedup vs baseline: 11.5191x; 1.1000x over previous
//
#include <hip/hip_runtime.h>
#include <math.h>

#define SEQ 4096
#define DM 512
#define NH 8
#define DH 64
#define TQK (3 * DM)   // 1536

typedef __attribute__((ext_vector_type(8))) short bf16x8;
typedef __attribute__((ext_vector_type(4))) float floatx4;
typedef unsigned short ushort_t;

__device__ __forceinline__ floatx4 mfma16(bf16x8 a, bf16x8 b, floatx4 c) {
    return __builtin_amdgcn_mfma_f32_16x16x32_bf16(a, b, c, 0, 0, 0);
}

// fp32 -> bf16 round-to-nearest-even
__device__ __forceinline__ unsigned int pk2(float a, float b) {
    unsigned int ua = __float_as_uint(a); ua = (ua + 0x7FFFu + ((ua >> 16) & 1u)) >> 16;
    unsigned int ub = __float_as_uint(b); ub = (ub + 0x7FFFu + ((ub >> 16) & 1u)) >> 16;
    return ua | (ub << 16);
}
__device__ __forceinline__ unsigned short f2bf(float x) {
    unsigned int u = __float_as_uint(x);
    return (unsigned short)((u + 0x7FFFu + ((u >> 16) & 1u)) >> 16);
}
__device__ __forceinline__ float bflo(unsigned int u) { return __uint_as_float(u << 16); }
__device__ __forceinline__ float bfhi(unsigned int u) { return __uint_as_float(u & 0xFFFF0000u); }

// async global->LDS, 16 B per lane; LDS dest = wave-uniform base + lane*16
__device__ __forceinline__ void gload_lds16(const void* g, void* l) {
    __builtin_amdgcn_global_load_lds(
        (const __attribute__((address_space(1))) unsigned int*)g,
        (__attribute__((address_space(3))) unsigned int*)l, 16, 0, 0);
}

// max over the 16-lane row via DPP butterfly (VALU pipe, no LDS):
// quad_perm xor1 (0xB1), quad_perm xor2 (0x4E), row_half_mirror (0x141), row_mirror (0x140)
#define DPPMAX(x, ctrl) \
    (x) = fmaxf((x), __int_as_float(__builtin_amdgcn_update_dpp(0, __float_as_int(x), (ctrl), 0xF, 0xF, true)))
__device__ __forceinline__ float row_max16(float x) {
    DPPMAX(x, 0xB1);
    DPPMAX(x, 0x4E);
    DPPMAX(x, 0x141);
    DPPMAX(x, 0x140);
    return x;
}

// ---------------- fp32 -> bf16 bulk convert (8 floats / thread) ----------------
__global__ __launch_bounds__(256) void f2bf_vec(const float* __restrict__ in,
                                                ushort_t* __restrict__ out) {
    const int i = blockIdx.x * 256 + threadIdx.x;
    const float4* p = (const float4*)in + (size_t)i * 2;
    float4 f0 = p[0], f1 = p[1];
    ((uint4*)out)[i] = make_uint4(pk2(f0.x, f0.y), pk2(f0.z, f0.w),
                                  pk2(f1.x, f1.y), pk2(f1.z, f1.w));
}

// ---------------- W [K x N] fp32 -> WT [N x K] bf16 (rows n < scale_below get x0.125) ----
__global__ __launch_bounds__(256) void wt_bf16(const float* __restrict__ W,
                                               ushort_t* __restrict__ WT,
                                               int K, int N, int scale_below) {
    __shared__ float T[64][65];   // [n-local][k-local]
    const int tid = threadIdx.x;
    const int k0 = blockIdx.y * 64, n0 = blockIdx.x * 64;
    {
        const int r = tid >> 2, g = tid & 3;
        const float* src = W + (size_t)(k0 + r) * N + n0 + g * 16;
#pragma unroll
        for (int i = 0; i < 4; i++) {
            float4 f = ((const float4*)src)[i];
            T[g * 16 + i * 4 + 0][r] = f.x;
            T[g * 16 + i * 4 + 1][r] = f.y;
            T[g * 16 + i * 4 + 2][r] = f.z;
            T[g * 16 + i * 4 + 3][r] = f.w;
        }
    }
    __syncthreads();
    const int nr = tid >> 2, g2 = tid & 3;
    const float sc = (n0 + nr < scale_below) ? 0.125f : 1.0f;
    unsigned int pk[8];
#pragma unroll
    for (int j = 0; j < 8; j++)
        pk[j] = pk2(T[nr][g2 * 16 + 2 * j] * sc, T[nr][g2 * 16 + 2 * j + 1] * sc);
    ushort_t* dst = WT + (size_t)(n0 + nr) * K + k0 + g2 * 16;
    ((uint4*)dst)[0] = make_uint4(pk[0], pk[1], pk[2], pk[3]);
    ((uint4*)dst)[1] = make_uint4(pk[4], pk[5], pk[6], pk[7]);
}

// ---------------- bf16 MFMA GEMM:  C = A @ BT^T + bias ----------------
// A [M x K] bf16, BT [N x K] bf16. 128x64 tile, BK=64, 256 threads (4 waves,
// 2x2 wave grid; wave = 64 rows x 32 cols, 4x2 mfma). XOR-chunk LDS swizzle.
// If vt_out != null and col0 >= 1024 (V region of qkv), the tile is stored
// TRANSPOSED (bf16) to vt_out[(n-1024)*SEQ + m] instead of Cv.
template <bool OUT_BF16>
__global__ __launch_bounds__(256) void gemm_mfma(const ushort_t* __restrict__ A,
                                                 const ushort_t* __restrict__ BT,
                                                 const float* __restrict__ bias,
                                                 void* __restrict__ Cv,
                                                 ushort_t* __restrict__ vt_out,
                                                 int M, int N, int K, int scale_below) {
    __shared__ __align__(16) ushort_t As[128 * 64];
    __shared__ __align__(16) ushort_t Bs[64 * 64];
    const int tid  = threadIdx.x;
    const int lane = tid & 63;
    const int w    = tid >> 6;
    const int quad = lane >> 4;
    const int ln   = lane & 15;
    const int row0 = blockIdx.y * 128;
    const int col0 = blockIdx.x * 64;
    const int wm = w >> 1, wn = w & 1;

    const int srow = lane >> 3;             // 0..7 row-in-group
    const int js   = (lane & 7) ^ srow;     // swizzled source chunk

    floatx4 acc[4][2];
#pragma unroll
    for (int i = 0; i < 4; i++)
#pragma unroll
        for (int j = 0; j < 2; j++) acc[i][j] = (floatx4){0.f, 0.f, 0.f, 0.f};

    for (int k0 = 0; k0 < K; k0 += 64) {
        __syncthreads();
#pragma unroll
        for (int i = 0; i < 4; i++) {
            const int c = w * 4 + i;        // 0..15 A 8-row group
            gload_lds16(A + (size_t)(row0 + c * 8 + srow) * K + k0 + js * 8, &As[c * 512]);
        }
#pragma unroll
        for (int i = 0; i < 2; i++) {
            const int c = w * 2 + i;        // 0..7 B 8-row group
            gload_lds16(BT + (size_t)(col0 + c * 8 + srow) * K + k0 + js * 8, &Bs[c * 512]);
        }
        __syncthreads();

#pragma unroll
        for (int s = 0; s < 2; s++) {
            bf16x8 af[4], bfr[2];
#pragma unroll
            for (int i = 0; i < 4; i++) {
                const int lm = wm * 64 + i * 16 + ln;
                af[i] = *(const bf16x8*)&As[lm * 64 + ((s * 4 + quad) ^ (ln & 7)) * 8];
            }
#pragma unroll
            for (int j = 0; j < 2; j++) {
                const int lnn = wn * 32 + j * 16 + ln;
                bfr[j] = *(const bf16x8*)&Bs[lnn * 64 + ((s * 4 + quad) ^ (ln & 7)) * 8];
            }
#pragma unroll
            for (int i = 0; i < 4; i++)
#pragma unroll
                for (int j = 0; j < 2; j++)
                    acc[i][j] = mfma16(af[i], bfr[j], acc[i][j]);
        }
    }

    if (vt_out && col0 >= 2 * DM) {
        // V region: store transposed bf16 to vt_out[(n-1024)*SEQ + m], 8B packed
#pragma unroll
        for (int j = 0; j < 2; j++) {
            const int n = col0 + wn * 32 + j * 16 + ln;
            const float bv = bias[n];
#pragma unroll
            for (int i = 0; i < 4; i++) {
                const int mb = row0 + wm * 64 + i * 16 + quad * 4;
                uint2 pkd;
                pkd.x = pk2(acc[i][j][0] + bv, acc[i][j][1] + bv);
                pkd.y = pk2(acc[i][j][2] + bv, acc[i][j][3] + bv);
                *(uint2*)&vt_out[(size_t)(n - 2 * DM) * SEQ + mb] = pkd;
            }
        }
        return;
    }

#pragma unroll
    for (int j = 0; j < 2; j++) {
        const int n = col0 + wn * 32 + j * 16 + ln;
        const float bv = bias[n] * ((n < scale_below) ? 0.125f : 1.0f);
#pragma unroll
        for (int i = 0; i < 4; i++) {
            const int mb = row0 + wm * 64 + i * 16 + quad * 4;
#pragma unroll
            for (int r = 0; r < 4; r++) {
                const float v = acc[i][j][r] + bv;
                if (OUT_BF16) ((ushort_t*)Cv)[(size_t)(mb + r) * N + n] = f2bf(v);
                else          ((float*)Cv)[(size_t)(mb + r) * N + n] = v;
            }
        }
    }
}

// ---------------- split-K MFMA flash attention ----------------
// Grid (160, 8): blockIdx.x enumerates (qt, chunk) pairs; chunks of <=16
// K-tiles. Writes unnormalized partial O (bf16) + per-row (m, l) (fp32).
__global__ __launch_bounds__(256) void attn_split(const ushort_t* __restrict__ qkv_b,
                                                  const ushort_t* __restrict__ vt,
                                                  ushort_t* __restrict__ po,
                                                  float2* __restrict__ pml) {
    __shared__ __align__(16) ushort_t Ks[64 * 64];   // swizzled, pitch 64
    __shared__ __align__(16) ushort_t Vs[64 * 64];   // [d][key], swizzled
    __shared__ __align__(16) ushort_t Ps[64 * 72];   // P slab, padded pitch

    const int tid  = threadIdx.x;
    const int lane = tid & 63;
    const int w    = tid >> 6;
    const int quad = lane >> 4;
    const int ln   = lane & 15;
    const int h    = blockIdx.y;

    // big-work chunks first
    const int e = 159 - (int)blockIdx.x;
    int qt, nc, c;
    if (e < 16)      { qt = e;                      nc = 1; c = 0; }
    else if (e < 48) { qt = 16 + ((e - 16) >> 1);   nc = 2; c = (e - 16) & 1; }
    else if (e < 96) { int u = e - 48; int q = u / 3; qt = 32 + q; nc = 3; c = u - 3 * q; }
    else             { int u = e - 96; qt = 48 + (u >> 2); nc = 4; c = u & 3; }
    const int T   = qt + 1;
    const int jt0 = (c * T) / nc;
    const int jt1 = ((c + 1) * T) / nc;
    const int q0  = qt * 64;

    // Q fragments straight from global (bf16, pre-scaled by 1/8 via W_in/b_in)
    const ushort_t* qrow = qkv_b + (size_t)(q0 + w * 16 + ln) * TQK + h * DH;
    const bf16x8 a0 = *(const bf16x8*)(qrow + quad * 8);
    const bf16x8 a1 = *(const bf16x8*)(qrow + quad * 8 + 32);

    const short oneb = (short)0x3F80;
    const bf16x8 vone = {oneb, oneb, oneb, oneb, oneb, oneb, oneb, oneb};

    float m_r[4];
    floatx4 o[4], ol;
#pragma unroll
    for (int r = 0; r < 4; r++) m_r[r] = -INFINITY;
#pragma unroll
    for (int t = 0; t < 4; t++) o[t] = (floatx4){0.f, 0.f, 0.f, 0.f};
    ol = (floatx4){0.f, 0.f, 0.f, 0.f};

    const int srow = lane >> 3;
    const int js   = (lane & 7) ^ srow;

    for (int jt = jt0; jt < jt1; ++jt) {
        const int k0 = jt * 64;
        __syncthreads();
#pragma unroll
        for (int i = 0; i < 2; i++) {
            const int cg = w * 2 + i;
            gload_lds16(qkv_b + (size_t)(k0 + cg * 8 + srow) * TQK + DM + h * DH + js * 8,
                        &Ks[cg * 512]);
            gload_lds16(vt + (size_t)(h * DH + cg * 8 + srow) * SEQ + k0 + js * 8,
                        &Vs[cg * 512]);
        }
        __syncthreads();

        // ---- S = Q K^T : 16x64 per wave (scores pre-scaled) ----
        floatx4 sa[4];
#pragma unroll
        for (int t = 0; t < 4; t++) {
            const int n = t * 16 + ln;
            const bf16x8 b0 = *(const bf16x8*)&Ks[n * 64 + ((quad) ^ (ln & 7)) * 8];
            const bf16x8 b1 = *(const bf16x8*)&Ks[n * 64 + ((4 + quad) ^ (ln & 7)) * 8];
            floatx4 acc = {0.f, 0.f, 0.f, 0.f};
            acc = mfma16(a0, b0, acc);
            acc = mfma16(a1, b1, acc);
            sa[t] = acc;
        }

        if (jt == qt) {   // diagonal tile: causal mask
#pragma unroll
            for (int t = 0; t < 4; t++) {
                const int cg = t * 16 + ln;
#pragma unroll
                for (int r = 0; r < 4; r++) {
                    const int rg = w * 16 + quad * 4 + r;
                    if (cg > rg) sa[t][r] = -INFINITY;
                }
            }
        }

        // ---- online softmax: DPP row-max, exp, P to LDS; l via ones-MFMA ----
#pragma unroll
        for (int r = 0; r < 4; r++) {
            float mx = fmaxf(fmaxf(sa[0][r], sa[1][r]), fmaxf(sa[2][r], sa[3][r]));
            mx = row_max16(mx);
            const float mn = fmaxf(m_r[r], mx);
            const float alpha = __expf(m_r[r] - mn);
            m_r[r] = mn;
#pragma unroll
            for (int t = 0; t < 4; t++) {
                const float p = __expf(sa[t][r] - mn);
                Ps[(w * 16 + quad * 4 + r) * 72 + t * 16 + ln] = f2bf(p);
            }
#pragma unroll
            for (int t = 0; t < 4; t++) o[t][r] *= alpha;
            ol[r] *= alpha;
        }

        __builtin_amdgcn_wave_barrier();   // order P writes before A-frag reads

        const bf16x8 p0 = *(const bf16x8*)&Ps[(w * 16 + ln) * 72 + quad * 8];
        const bf16x8 p1 = *(const bf16x8*)&Ps[(w * 16 + ln) * 72 + quad * 8 + 32];
#pragma unroll
        for (int t = 0; t < 4; t++) {
            const int d = t * 16 + ln;
            const bf16x8 v0 = *(const bf16x8*)&Vs[d * 64 + ((quad) ^ (ln & 7)) * 8];
            const bf16x8 v1 = *(const bf16x8*)&Vs[d * 64 + ((4 + quad) ^ (ln & 7)) * 8];
            o[t] = mfma16(p0, v0, o[t]);
            o[t] = mfma16(p1, v1, o[t]);
        }
        ol = mfma16(p0, vone, ol);
        ol = mfma16(p1, vone, ol);   // row-sum of P, same rescale path as o
    }

    // ---- partials: unnormalized bf16 O, fp32 (m, l) ----
    const size_t pbase  = (((size_t)h * 64 + qt) * 4 + c) * (64 * 64);
    const size_t mlbase = (((size_t)h * 64 + qt) * 4 + c) * 64;
#pragma unroll
    for (int t = 0; t < 4; t++)
#pragma unroll
        for (int r = 0; r < 4; r++)
            po[pbase + (size_t)(w * 16 + quad * 4 + r) * 64 + t * 16 + ln] = f2bf(o[t][r]);
    if (ln == 0) {
#pragma unroll
        for (int r = 0; r < 4; r++)
            pml[mlbase + w * 16 + quad * 4 + r] = make_float2(m_r[r], ol[r]);
    }
}

// ---------------- combine partials -> attn_out bf16 [SEQ][DM] ----------------
__global__ __launch_bounds__(256) void attn_combine(const ushort_t* __restrict__ po,
                                                    const float2* __restrict__ pml,
                                                    ushort_t* __restrict__ aob) {
    const int qt = blockIdx.x, h = blockIdx.y;
    const int nc = (qt >> 4) + 1;
    const int row = threadIdx.x >> 2, g = threadIdx.x & 3;
    const size_t base   = (((size_t)h * 64 + qt) * 4) * (64 * 64);
    const size_t mlbase = (((size_t)h * 64 + qt) * 4) * 64;

    float2 ml[4];
    float M = -INFINITY;
    for (int cidx = 0; cidx < nc; cidx++) {
        ml[cidx] = pml[mlbase + (size_t)cidx * 64 + row];
        M = fmaxf(M, ml[cidx].x);
    }
    float L = 0.f;
    float acc[16];
#pragma unroll
    for (int j = 0; j < 16; j++) acc[j] = 0.f;

    for (int cidx = 0; cidx < nc; cidx++) {
        const float wgt = __expf(ml[cidx].x - M);
        L += wgt * ml[cidx].y;
        const ushort_t* p = po + base + (size_t)cidx * 4096 + (size_t)row * 64 + g * 16;
        uint4 u0 = ((const uint4*)p)[0];
        uint4 u1 = ((const uint4*)p)[1];
        const unsigned int uu[8] = {u0.x, u0.y, u0.z, u0.w, u1.x, u1.y, u1.z, u1.w};
#pragma unroll
        for (int j = 0; j < 8; j++) {
            acc[2 * j]     += wgt * bflo(uu[j]);
            acc[2 * j + 1] += wgt * bfhi(uu[j]);
        }
    }
    const float inv = 1.0f / L;
    unsigned int pk[8];
#pragma unroll
    for (int j = 0; j < 8; j++)
        pk[j] = pk2(acc[2 * j] * inv, acc[2 * j + 1] * inv);
    ushort_t* dst = aob + (size_t)(qt * 64 + row) * DM + h * DH + g * 16;
    ((uint4*)dst)[0] = make_uint4(pk[0], pk[1], pk[2], pk[3]);
    ((uint4*)dst)[1] = make_uint4(pk[4], pk[5], pk[6], pk[7]);
}

extern "C" void kernel_launch(void* const* d_in, const int* in_sizes, int n_in,
                              void* d_out, int out_size, void* d_ws, size_t ws_size,
                              hipStream_t stream) {
    const float* x     = (const float*)d_in[0];
    const float* W_in  = (const float*)d_in[1];
    const float* b_in  = (const float*)d_in[2];
    const float* W_out = (const float*)d_in[3];
    const float* b_out = (const float*)d_in[4];
    float* out = (float*)d_out;

    // workspace layout (MB offsets)
    char* ws = (char*)d_ws;
    ushort_t* xb    = (ushort_t*)ws;                    //  4 MB  x bf16 [4096][512]
    ushort_t* wti   = (ushort_t*)(ws + (4u  << 20));    //  1.5MB W_in^T bf16 (Q cols pre-scaled 1/8)
    ushort_t* wto   = (ushort_t*)(ws + (6u  << 20));    //  0.5MB W_out^T bf16
    ushort_t* qkv_b = (ushort_t*)(ws + (7u  << 20));    // 12 MB  qkv bf16 (V third unused)
    ushort_t* vtb   = (ushort_t*)(ws + (19u << 20));    //  4 MB  V^T bf16 [8*64][4096]
    ushort_t* aob   = (ushort_t*)(ws + (23u << 20));    //  4 MB  attn out bf16
    ushort_t* po    = (ushort_t*)(ws + (27u << 20));    // 16 MB  partial O bf16 [8][64][4][64][64]
    float2*   pml   = (float2*)  (ws + (43u << 20));    //  1 MB  partial (m,l)

    // 0) conversions / transposes
    f2bf_vec<<<SEQ * DM / 8 / 256, 256, 0, stream>>>(x, xb);
    wt_bf16<<<dim3(TQK / 64, DM / 64), 256, 0, stream>>>(W_in, wti, DM, TQK, DM);
    wt_bf16<<<dim3(DM / 64, DM / 64), 256, 0, stream>>>(W_out, wto, DM, DM, 0);

    // 1) qkv = x @ W_in + b_in; Q pre-scaled; V written transposed to vtb
    gemm_mfma<true><<<dim3(TQK / 64, SEQ / 128), 256, 0, stream>>>(
        xb, wti, b_in, qkv_b, vtb, SEQ, TQK, DM, DM);

    // 2) split-K causal flash attention -> partials
    attn_split<<<dim3(160, NH), 256, 0, stream>>>(qkv_b, vtb, po, pml);

    // 3) merge partials
    attn_combine<<<dim3(SEQ / 64, NH), 256, 0, stream>>>(po, pml, aob);

    // 4) out = attn_out @ W_out + b_out (fp32)
    gemm_mfma<false><<<dim3(DM / 64, SEQ / 128), 256, 0, stream>>>(
        aob, wto, b_out, out, nullptr, SEQ, DM, DM, 0);
}

// Round 5
// 173.722 us; speedup vs baseline: 12.4819x; 1.0836x over previous
//
#include <hip/hip_runtime.h>
#include <math.h>

#define SEQ 4096
#define DM 512
#define NH 8
#define DH 64
#define TQK (3 * DM)   // 1536
#define QSCALE 0.18033688011112042f   // log2(e)/8 : folds softmax scale + base-2 exp

typedef __attribute__((ext_vector_type(8))) short bf16x8;
typedef __attribute__((ext_vector_type(4))) float floatx4;
typedef unsigned short ushort_t;

__device__ __forceinline__ floatx4 mfma16(bf16x8 a, bf16x8 b, floatx4 c) {
    return __builtin_amdgcn_mfma_f32_16x16x32_bf16(a, b, c, 0, 0, 0);
}
__device__ __forceinline__ float ex2(float x) { return __builtin_amdgcn_exp2f(x); }

// fp32 -> bf16 round-to-nearest-even (pack 2)
__device__ __forceinline__ unsigned int pk2(float a, float b) {
    unsigned int ua = __float_as_uint(a); ua = (ua + 0x7FFFu + ((ua >> 16) & 1u)) >> 16;
    unsigned int ub = __float_as_uint(b); ub = (ub + 0x7FFFu + ((ub >> 16) & 1u)) >> 16;
    return ua | (ub << 16);
}
__device__ __forceinline__ unsigned short f2bf(float x) {
    unsigned int u = __float_as_uint(x);
    return (unsigned short)((u + 0x7FFFu + ((u >> 16) & 1u)) >> 16);
}
__device__ __forceinline__ float bflo(unsigned int u) { return __uint_as_float(u << 16); }
__device__ __forceinline__ float bfhi(unsigned int u) { return __uint_as_float(u & 0xFFFF0000u); }

__device__ __forceinline__ void gload_lds16(const void* g, void* l) {
    __builtin_amdgcn_global_load_lds(
        (const __attribute__((address_space(1))) unsigned int*)g,
        (__attribute__((address_space(3))) unsigned int*)l, 16, 0, 0);
}

// per-quad (16-lane DPP row) max butterfly
#define DPPMAX(x, ctrl) \
    (x) = fmaxf((x), __int_as_float(__builtin_amdgcn_update_dpp(0, __float_as_int(x), (ctrl), 0xF, 0xF, true)))
__device__ __forceinline__ float row_max16(float x) {
    DPPMAX(x, 0xB1);   // quad_perm xor1
    DPPMAX(x, 0x4E);   // quad_perm xor2
    DPPMAX(x, 0x141);  // row_half_mirror
    DPPMAX(x, 0x140);  // row_mirror
    return x;
}

// ---------------- fused prep: x->bf16, W_in^T (Q cols pre-scaled), W_out^T ----------------
__global__ __launch_bounds__(256) void prep(const float* __restrict__ x,
                                            const float* __restrict__ W_in,
                                            const float* __restrict__ W_out,
                                            ushort_t* __restrict__ xb,
                                            ushort_t* __restrict__ wti,
                                            ushort_t* __restrict__ wto) {
    __shared__ float T[64][65];
    const int bid = blockIdx.x, tid = threadIdx.x;
    if (bid < 1024) {   // x [4096x512] fp32 -> bf16, 2048 elems/block
        const int i = bid * 256 + tid;
        const float4* p = (const float4*)x + (size_t)i * 2;
        float4 f0 = p[0], f1 = p[1];
        ((uint4*)xb)[i] = make_uint4(pk2(f0.x, f0.y), pk2(f0.z, f0.w),
                                     pk2(f1.x, f1.y), pk2(f1.z, f1.w));
        return;
    }
    const float* W; ushort_t* WT; int N, K, n0, k0; bool qscale;
    if (bid < 1216) { int id = bid - 1024; W = W_in;  WT = wti; N = TQK; K = DM;
                      n0 = (id % 24) * 64; k0 = (id / 24) * 64; qscale = true; }
    else            { int id = bid - 1216; W = W_out; WT = wto; N = DM;  K = DM;
                      n0 = (id % 8) * 64;  k0 = (id / 8) * 64;  qscale = false; }
    {
        const int r = tid >> 2, g = tid & 3;
        const float* src = W + (size_t)(k0 + r) * N + n0 + g * 16;
#pragma unroll
        for (int i = 0; i < 4; i++) {
            float4 f = ((const float4*)src)[i];
            T[g * 16 + i * 4 + 0][r] = f.x;
            T[g * 16 + i * 4 + 1][r] = f.y;
            T[g * 16 + i * 4 + 2][r] = f.z;
            T[g * 16 + i * 4 + 3][r] = f.w;
        }
    }
    __syncthreads();
    const int nr = tid >> 2, g2 = tid & 3;
    const float sc = (qscale && (n0 + nr < DM)) ? QSCALE : 1.0f;
    unsigned int pk[8];
#pragma unroll
    for (int j = 0; j < 8; j++)
        pk[j] = pk2(T[nr][g2 * 16 + 2 * j] * sc, T[nr][g2 * 16 + 2 * j + 1] * sc);
    ushort_t* dst = WT + (size_t)(n0 + nr) * K + k0 + g2 * 16;
    ((uint4*)dst)[0] = make_uint4(pk[0], pk[1], pk[2], pk[3]);
    ((uint4*)dst)[1] = make_uint4(pk[4], pk[5], pk[6], pk[7]);
}

// ---------------- bf16 MFMA GEMM, 128x128 tile, BK=64, double-buffered 1-barrier ----------
// A [M x K], BT [N x K]. If vt_out != null and col0 >= 1024 (V region), tile is
// stored transposed (bias applied, bf16) to vt_out[(n-1024)*SEQ + m].
template <bool OUT_BF16>
__global__ __launch_bounds__(256) void gemm128(const ushort_t* __restrict__ A,
                                               const ushort_t* __restrict__ BT,
                                               const float* __restrict__ bias,
                                               void* __restrict__ Cv,
                                               ushort_t* __restrict__ vt_out,
                                               int N, int K, int scale_q) {
    __shared__ __align__(16) ushort_t As[2][128 * 64];
    __shared__ __align__(16) ushort_t Bs[2][128 * 64];
    const int tid  = threadIdx.x;
    const int lane = tid & 63;
    const int w    = tid >> 6;
    const int quad = lane >> 4;
    const int ln   = lane & 15;
    const int row0 = blockIdx.y * 128;
    const int col0 = blockIdx.x * 128;
    const int wm = w >> 1, wn = w & 1;

    const int srow = lane >> 3;             // row within 8-row staging group
    const int js   = (lane & 7) ^ srow;     // swizzled source chunk

    floatx4 acc[4][4];
#pragma unroll
    for (int i = 0; i < 4; i++)
#pragma unroll
        for (int j = 0; j < 4; j++) acc[i][j] = (floatx4){0.f, 0.f, 0.f, 0.f};

    const int nsteps = K >> 6;
    // prologue: stage step 0 into buffer 0
#pragma unroll
    for (int i = 0; i < 4; i++) {
        const int c = w * 4 + i;
        gload_lds16(A  + (size_t)(row0 + c * 8 + srow) * K + js * 8, &As[0][c * 512]);
        gload_lds16(BT + (size_t)(col0 + c * 8 + srow) * K + js * 8, &Bs[0][c * 512]);
    }

    for (int kt = 0; kt < nsteps; kt++) {
        const int cur = kt & 1;
        __syncthreads();   // drains cur loads; all waves done reading buf cur^1
        if (kt + 1 < nsteps) {
            const int k0n = (kt + 1) << 6;
#pragma unroll
            for (int i = 0; i < 4; i++) {
                const int c = w * 4 + i;
                gload_lds16(A  + (size_t)(row0 + c * 8 + srow) * K + k0n + js * 8, &As[cur ^ 1][c * 512]);
                gload_lds16(BT + (size_t)(col0 + c * 8 + srow) * K + k0n + js * 8, &Bs[cur ^ 1][c * 512]);
            }
        }
#pragma unroll
        for (int s = 0; s < 2; s++) {
            bf16x8 af[4], bfr[4];
#pragma unroll
            for (int i = 0; i < 4; i++) {
                const int lm = wm * 64 + i * 16 + ln;
                af[i] = *(const bf16x8*)&As[cur][lm * 64 + ((s * 4 + quad) ^ (ln & 7)) * 8];
                const int lnn = wn * 64 + i * 16 + ln;
                bfr[i] = *(const bf16x8*)&Bs[cur][lnn * 64 + ((s * 4 + quad) ^ (ln & 7)) * 8];
            }
#pragma unroll
            for (int i = 0; i < 4; i++)
#pragma unroll
                for (int j = 0; j < 4; j++)
                    acc[i][j] = mfma16(af[i], bfr[j], acc[i][j]);
        }
    }

    if (vt_out && col0 >= 2 * DM) {
#pragma unroll
        for (int j = 0; j < 4; j++) {
            const int n = col0 + wn * 64 + j * 16 + ln;
            const float bv = bias[n];
#pragma unroll
            for (int i = 0; i < 4; i++) {
                const int mb = row0 + wm * 64 + i * 16 + quad * 4;
                uint2 pkd;
                pkd.x = pk2(acc[i][j][0] + bv, acc[i][j][1] + bv);
                pkd.y = pk2(acc[i][j][2] + bv, acc[i][j][3] + bv);
                *(uint2*)&vt_out[(size_t)(n - 2 * DM) * SEQ + mb] = pkd;
            }
        }
        return;
    }

#pragma unroll
    for (int j = 0; j < 4; j++) {
        const int n = col0 + wn * 64 + j * 16 + ln;
        const float bv = bias[n] * ((scale_q && n < DM) ? QSCALE : 1.0f);
#pragma unroll
        for (int i = 0; i < 4; i++) {
            const int mb = row0 + wm * 64 + i * 16 + quad * 4;
#pragma unroll
            for (int r = 0; r < 4; r++) {
                const float v = acc[i][j][r] + bv;
                if (OUT_BF16) ((ushort_t*)Cv)[(size_t)(mb + r) * N + n] = f2bf(v);
                else          ((float*)Cv)[(size_t)(mb + r) * N + n] = v;
            }
        }
    }
}

// ---------------- split-K MFMA flash attention, dbuf 1-barrier pipeline ----------------
// Grid (288, 8). Slot e = 287-bx enumerates (qt, chunk): group k (=nc) covers
// qt in [8(k-1), 8k), slots [4k(k-1), 4k(k+1)). Chunks are <=8 K-tiles.
__global__ __launch_bounds__(256) void attn_split(const ushort_t* __restrict__ qkv_b,
                                                  const ushort_t* __restrict__ vt,
                                                  ushort_t* __restrict__ po,
                                                  float2* __restrict__ pml) {
    __shared__ __align__(16) ushort_t Ks[2][64 * 64];
    __shared__ __align__(16) ushort_t Vs[2][64 * 64];
    __shared__ __align__(16) ushort_t Ps[64 * 72];

    const int tid  = threadIdx.x;
    const int lane = tid & 63;
    const int w    = tid >> 6;
    const int quad = lane >> 4;
    const int ln   = lane & 15;
    const int h    = blockIdx.y;

    const int e = 287 - (int)blockIdx.x;
    int k = 1;
    while (e >= 4 * k * (k + 1)) k++;
    const int off = e - 4 * k * (k - 1);
    const int qt  = 8 * (k - 1) + off / k;
    const int c   = off % k;
    const int nc  = k;
    const int T   = qt + 1;
    const int jt0 = (c * T) / nc;
    const int jt1 = ((c + 1) * T) / nc;
    const int q0  = qt * 64;

    // Q fragments straight from global (bf16, pre-scaled by log2e/8)
    const ushort_t* qrow = qkv_b + (size_t)(q0 + w * 16 + ln) * TQK + h * DH;
    const bf16x8 a0 = *(const bf16x8*)(qrow + quad * 8);
    const bf16x8 a1 = *(const bf16x8*)(qrow + quad * 8 + 32);

    const short oneb = (short)0x3F80;
    const bf16x8 vone = {oneb, oneb, oneb, oneb, oneb, oneb, oneb, oneb};

    float m_q = -INFINITY;           // shared max for this quad's 4 rows (exact renorm)
    floatx4 o[4], ol;
#pragma unroll
    for (int t = 0; t < 4; t++) o[t] = (floatx4){0.f, 0.f, 0.f, 0.f};
    ol = (floatx4){0.f, 0.f, 0.f, 0.f};

    const int srow = lane >> 3;
    const int js   = (lane & 7) ^ srow;

    // prologue: stage jt0 into buffer 0
    {
        const int k0 = jt0 * 64;
#pragma unroll
        for (int i = 0; i < 2; i++) {
            const int cg = w * 2 + i;
            gload_lds16(qkv_b + (size_t)(k0 + cg * 8 + srow) * TQK + DM + h * DH + js * 8,
                        &Ks[0][cg * 512]);
            gload_lds16(vt + (size_t)(h * DH + cg * 8 + srow) * SEQ + k0 + js * 8,
                        &Vs[0][cg * 512]);
        }
    }

    for (int jt = jt0; jt < jt1; ++jt) {
        const int cur = (jt - jt0) & 1;
        __syncthreads();   // drains cur's loads; everyone done reading buf cur^1
        if (jt + 1 < jt1) {
            const int k0n = (jt + 1) * 64;
#pragma unroll
            for (int i = 0; i < 2; i++) {
                const int cg = w * 2 + i;
                gload_lds16(qkv_b + (size_t)(k0n + cg * 8 + srow) * TQK + DM + h * DH + js * 8,
                            &Ks[cur ^ 1][cg * 512]);
                gload_lds16(vt + (size_t)(h * DH + cg * 8 + srow) * SEQ + k0n + js * 8,
                            &Vs[cur ^ 1][cg * 512]);
            }
        }

        // ---- S = Q K^T (pre-scaled, base-2 domain) ----
        floatx4 sa[4];
#pragma unroll
        for (int t = 0; t < 4; t++) {
            const int n = t * 16 + ln;
            const bf16x8 b0 = *(const bf16x8*)&Ks[cur][n * 64 + ((quad) ^ (ln & 7)) * 8];
            const bf16x8 b1 = *(const bf16x8*)&Ks[cur][n * 64 + ((4 + quad) ^ (ln & 7)) * 8];
            floatx4 acc = {0.f, 0.f, 0.f, 0.f};
            acc = mfma16(a0, b0, acc);
            acc = mfma16(a1, b1, acc);
            sa[t] = acc;
        }

        if (jt == qt) {   // diagonal tile: causal mask
#pragma unroll
            for (int t = 0; t < 4; t++) {
                const int cg2 = t * 16 + ln;
#pragma unroll
                for (int r = 0; r < 4; r++) {
                    const int rg = w * 16 + quad * 4 + r;
                    if (cg2 > rg) sa[t][r] = -INFINITY;
                }
            }
        }

        // ---- online softmax: one shared max per quad (4 rows) ----
        float mx = sa[0][0];
#pragma unroll
        for (int t = 0; t < 4; t++)
#pragma unroll
            for (int r = 0; r < 4; r++) mx = fmaxf(mx, sa[t][r]);
        mx = row_max16(mx);
        const float mn = fmaxf(m_q, mx);
        const float alpha = ex2(m_q - mn);   // 0 on first tile
        m_q = mn;
#pragma unroll
        for (int t = 0; t < 4; t++)
#pragma unroll
            for (int r = 0; r < 4; r++) {
                const float p = ex2(sa[t][r] - mn);
                // truncating bf16 pack (1 op); P>=0 so trunc error <= 2^-8 rel
                Ps[(w * 16 + quad * 4 + r) * 72 + t * 16 + ln] =
                    (ushort_t)(__float_as_uint(p) >> 16);
            }
        if (alpha < 1.0f) {
#pragma unroll
            for (int t = 0; t < 4; t++)
#pragma unroll
                for (int r = 0; r < 4; r++) o[t][r] *= alpha;
#pragma unroll
            for (int r = 0; r < 4; r++) ol[r] *= alpha;
        }

        __builtin_amdgcn_wave_barrier();   // order P writes before A-frag reads (same wave)

        const bf16x8 p0 = *(const bf16x8*)&Ps[(w * 16 + ln) * 72 + quad * 8];
        const bf16x8 p1 = *(const bf16x8*)&Ps[(w * 16 + ln) * 72 + quad * 8 + 32];
#pragma unroll
        for (int t = 0; t < 4; t++) {
            const int d = t * 16 + ln;
            const bf16x8 v0 = *(const bf16x8*)&Vs[cur][d * 64 + ((quad) ^ (ln & 7)) * 8];
            const bf16x8 v1 = *(const bf16x8*)&Vs[cur][d * 64 + ((4 + quad) ^ (ln & 7)) * 8];
            o[t] = mfma16(p0, v0, o[t]);
            o[t] = mfma16(p1, v1, o[t]);
        }
        ol = mfma16(p0, vone, ol);
        ol = mfma16(p1, vone, ol);
    }

    // partials: unnormalized bf16 O + fp32 (m, l); slot index == e
    const size_t pbase  = ((size_t)h * 288 + e) * 4096;
    const size_t mlbase = ((size_t)h * 288 + e) * 64;
#pragma unroll
    for (int t = 0; t < 4; t++)
#pragma unroll
        for (int r = 0; r < 4; r++)
            po[pbase + (size_t)(w * 16 + quad * 4 + r) * 64 + t * 16 + ln] = f2bf(o[t][r]);
    if (ln == 0) {
#pragma unroll
        for (int r = 0; r < 4; r++)
            pml[mlbase + w * 16 + quad * 4 + r] = make_float2(m_q, ol[r]);
    }
}

// ---------------- combine partials -> attn_out bf16 [SEQ][DM] ----------------
__global__ __launch_bounds__(256) void attn_combine(const ushort_t* __restrict__ po,
                                                    const float2* __restrict__ pml,
                                                    ushort_t* __restrict__ aob) {
    const int qt = blockIdx.x, h = blockIdx.y;
    const int k = (qt >> 3) + 1;
    const int sbase = 4 * k * (k - 1) + (qt & 7) * k;
    const int nc = k;
    const int row = threadIdx.x >> 2, g = threadIdx.x & 3;

    float2 ml[8];
    float M = -INFINITY;
    for (int cidx = 0; cidx < nc; cidx++) {
        ml[cidx] = pml[((size_t)h * 288 + sbase + cidx) * 64 + row];
        M = fmaxf(M, ml[cidx].x);
    }
    float L = 0.f;
    float acc[16];
#pragma unroll
    for (int j = 0; j < 16; j++) acc[j] = 0.f;

    for (int cidx = 0; cidx < nc; cidx++) {
        const float wgt = ex2(ml[cidx].x - M);
        L += wgt * ml[cidx].y;
        const ushort_t* p = po + ((size_t)h * 288 + sbase + cidx) * 4096 + (size_t)row * 64 + g * 16;
        uint4 u0 = ((const uint4*)p)[0];
        uint4 u1 = ((const uint4*)p)[1];
        const unsigned int uu[8] = {u0.x, u0.y, u0.z, u0.w, u1.x, u1.y, u1.z, u1.w};
#pragma unroll
        for (int j = 0; j < 8; j++) {
            acc[2 * j]     += wgt * bflo(uu[j]);
            acc[2 * j + 1] += wgt * bfhi(uu[j]);
        }
    }
    const float inv = 1.0f / L;
    unsigned int pk[8];
#pragma unroll
    for (int j = 0; j < 8; j++)
        pk[j] = pk2(acc[2 * j] * inv, acc[2 * j + 1] * inv);
    ushort_t* dst = aob + (size_t)(qt * 64 + row) * DM + h * DH + g * 16;
    ((uint4*)dst)[0] = make_uint4(pk[0], pk[1], pk[2], pk[3]);
    ((uint4*)dst)[1] = make_uint4(pk[4], pk[5], pk[6], pk[7]);
}

extern "C" void kernel_launch(void* const* d_in, const int* in_sizes, int n_in,
                              void* d_out, int out_size, void* d_ws, size_t ws_size,
                              hipStream_t stream) {
    const float* x     = (const float*)d_in[0];
    const float* W_in  = (const float*)d_in[1];
    const float* b_in  = (const float*)d_in[2];
    const float* W_out = (const float*)d_in[3];
    const float* b_out = (const float*)d_in[4];
    float* out = (float*)d_out;

    char* ws = (char*)d_ws;
    ushort_t* xb    = (ushort_t*)ws;                    //  4 MB   x bf16 [4096][512]
    ushort_t* wti   = (ushort_t*)(ws + (4u  << 20));    //  1.5 MB W_in^T bf16 (Q cols x QSCALE)
    ushort_t* wto   = (ushort_t*)(ws + (6u  << 20));    //  0.5 MB W_out^T bf16
    ushort_t* qkv_b = (ushort_t*)(ws + (7u  << 20));    // 12 MB   qkv bf16 (V third unused)
    ushort_t* vtb   = (ushort_t*)(ws + (19u << 20));    //  4 MB   V^T bf16 [512][4096]
    ushort_t* aob   = (ushort_t*)(ws + (23u << 20));    //  4 MB   attn out bf16
    ushort_t* po    = (ushort_t*)(ws + (27u << 20));    // 18.9 MB partial O bf16 [8][288][4096]
    float2*   pml   = (float2*)  (ws + (46u << 20));    //  1.2 MB partial (m,l)

    // 0) fused prep: x->bf16 | W_in^T | W_out^T
    prep<<<1280, 256, 0, stream>>>(x, W_in, W_out, xb, wti, wto);

    // 1) qkv = x @ W_in + b_in; Q pre-scaled; V diverted transposed to vtb
    gemm128<true><<<dim3(TQK / 128, SEQ / 128), 256, 0, stream>>>(
        xb, wti, b_in, qkv_b, vtb, TQK, DM, 1);

    // 2) split-K causal flash attention -> partials
    attn_split<<<dim3(288, NH), 256, 0, stream>>>(qkv_b, vtb, po, pml);

    // 3) merge partials
    attn_combine<<<dim3(SEQ / 64, NH), 256, 0, stream>>>(po, pml, aob);

    // 4) out = attn_out @ W_out + b_out (fp32)
    gemm128<false><<<dim3(DM / 128, SEQ / 128), 256, 0, stream>>>(
        aob, wto, b_out, out, nullptr, DM, DM, 0);
}

// Round 6
// 173.412 us; speedup vs baseline: 12.5043x; 1.0018x over previous
//
#include <hip/hip_runtime.h>
#include <math.h>

#define SEQ 4096
#define DM 512
#define NH 8
#define DH 64
#define TQK (3 * DM)   // 1536
#define QSCALE 0.18033688011112042f   // log2(e)/8 : folds softmax scale + base-2 exp

typedef __attribute__((ext_vector_type(8))) short bf16x8;
typedef __attribute__((ext_vector_type(4))) float floatx4;
typedef unsigned short ushort_t;

__device__ __forceinline__ floatx4 mfma16(bf16x8 a, bf16x8 b, floatx4 c) {
    return __builtin_amdgcn_mfma_f32_16x16x32_bf16(a, b, c, 0, 0, 0);
}
__device__ __forceinline__ float ex2(float x) { return __builtin_amdgcn_exp2f(x); }

__device__ __forceinline__ unsigned int pk2(float a, float b) {
    unsigned int ua = __float_as_uint(a); ua = (ua + 0x7FFFu + ((ua >> 16) & 1u)) >> 16;
    unsigned int ub = __float_as_uint(b); ub = (ub + 0x7FFFu + ((ub >> 16) & 1u)) >> 16;
    return ua | (ub << 16);
}
__device__ __forceinline__ unsigned short f2bf(float x) {
    unsigned int u = __float_as_uint(x);
    return (unsigned short)((u + 0x7FFFu + ((u >> 16) & 1u)) >> 16);
}
__device__ __forceinline__ float bflo(unsigned int u) { return __uint_as_float(u << 16); }
__device__ __forceinline__ float bfhi(unsigned int u) { return __uint_as_float(u & 0xFFFF0000u); }

__device__ __forceinline__ void gload_lds16(const void* g, void* l) {
    __builtin_amdgcn_global_load_lds(
        (const __attribute__((address_space(1))) unsigned int*)g,
        (__attribute__((address_space(3))) unsigned int*)l, 16, 0, 0);
}

#define DPPMAX(x, ctrl) \
    (x) = fmaxf((x), __int_as_float(__builtin_amdgcn_update_dpp(0, __float_as_int(x), (ctrl), 0xF, 0xF, true)))
__device__ __forceinline__ float row_max16(float x) {
    DPPMAX(x, 0xB1);   // quad_perm xor1
    DPPMAX(x, 0x4E);   // quad_perm xor2
    DPPMAX(x, 0x141);  // row_half_mirror
    DPPMAX(x, 0x140);  // row_mirror
    return x;
}

// ---------------- fused prep: x->bf16, W_in^T (Q cols pre-scaled), W_out^T ----------------
__global__ __launch_bounds__(256) void prep(const float* __restrict__ x,
                                            const float* __restrict__ W_in,
                                            const float* __restrict__ W_out,
                                            ushort_t* __restrict__ xb,
                                            ushort_t* __restrict__ wti,
                                            ushort_t* __restrict__ wto) {
    __shared__ float T[64][65];
    const int bid = blockIdx.x, tid = threadIdx.x;
    if (bid < 1024) {
        const int i = bid * 256 + tid;
        const float4* p = (const float4*)x + (size_t)i * 2;
        float4 f0 = p[0], f1 = p[1];
        ((uint4*)xb)[i] = make_uint4(pk2(f0.x, f0.y), pk2(f0.z, f0.w),
                                     pk2(f1.x, f1.y), pk2(f1.z, f1.w));
        return;
    }
    const float* W; ushort_t* WT; int N, K, n0, k0; bool qscale;
    if (bid < 1216) { int id = bid - 1024; W = W_in;  WT = wti; N = TQK; K = DM;
                      n0 = (id % 24) * 64; k0 = (id / 24) * 64; qscale = true; }
    else            { int id = bid - 1216; W = W_out; WT = wto; N = DM;  K = DM;
                      n0 = (id % 8) * 64;  k0 = (id / 8) * 64;  qscale = false; }
    {
        const int r = tid >> 2, g = tid & 3;
        const float* src = W + (size_t)(k0 + r) * N + n0 + g * 16;
#pragma unroll
        for (int i = 0; i < 4; i++) {
            float4 f = ((const float4*)src)[i];
            T[g * 16 + i * 4 + 0][r] = f.x;
            T[g * 16 + i * 4 + 1][r] = f.y;
            T[g * 16 + i * 4 + 2][r] = f.z;
            T[g * 16 + i * 4 + 3][r] = f.w;
        }
    }
    __syncthreads();
    const int nr = tid >> 2, g2 = tid & 3;
    const float sc = (qscale && (n0 + nr < DM)) ? QSCALE : 1.0f;
    unsigned int pk[8];
#pragma unroll
    for (int j = 0; j < 8; j++)
        pk[j] = pk2(T[nr][g2 * 16 + 2 * j] * sc, T[nr][g2 * 16 + 2 * j + 1] * sc);
    ushort_t* dst = WT + (size_t)(n0 + nr) * K + k0 + g2 * 16;
    ((uint4*)dst)[0] = make_uint4(pk[0], pk[1], pk[2], pk[3]);
    ((uint4*)dst)[1] = make_uint4(pk[4], pk[5], pk[6], pk[7]);
}

// ---------------- GEMM1: qkv = x @ W_in^T + b_in (bf16 out, V diverted transposed) -------
__global__ __launch_bounds__(256) void gemm_in(const ushort_t* __restrict__ A,
                                               const ushort_t* __restrict__ BT,
                                               const float* __restrict__ bias,
                                               ushort_t* __restrict__ Cv,
                                               ushort_t* __restrict__ vt_out) {
    __shared__ __align__(16) ushort_t As[2][128 * 64];
    __shared__ __align__(16) ushort_t Bs[2][128 * 64];
    const int tid  = threadIdx.x;
    const int lane = tid & 63;
    const int w    = tid >> 6;
    const int quad = lane >> 4;
    const int ln   = lane & 15;
    const int row0 = blockIdx.y * 128;
    const int col0 = blockIdx.x * 128;
    const int wm = w >> 1, wn = w & 1;
    const int srow = lane >> 3;
    const int js   = (lane & 7) ^ srow;
    const int K = DM, N = TQK;

    floatx4 acc[4][4];
#pragma unroll
    for (int i = 0; i < 4; i++)
#pragma unroll
        for (int j = 0; j < 4; j++) acc[i][j] = (floatx4){0.f, 0.f, 0.f, 0.f};

#pragma unroll
    for (int i = 0; i < 4; i++) {
        const int c = w * 4 + i;
        gload_lds16(A  + (size_t)(row0 + c * 8 + srow) * K + js * 8, &As[0][c * 512]);
        gload_lds16(BT + (size_t)(col0 + c * 8 + srow) * K + js * 8, &Bs[0][c * 512]);
    }

    for (int kt = 0; kt < 8; kt++) {
        const int cur = kt & 1;
        __syncthreads();
        if (kt < 7) {
            const int k0n = (kt + 1) << 6;
#pragma unroll
            for (int i = 0; i < 4; i++) {
                const int c = w * 4 + i;
                gload_lds16(A  + (size_t)(row0 + c * 8 + srow) * K + k0n + js * 8, &As[cur ^ 1][c * 512]);
                gload_lds16(BT + (size_t)(col0 + c * 8 + srow) * K + k0n + js * 8, &Bs[cur ^ 1][c * 512]);
            }
        }
#pragma unroll
        for (int s = 0; s < 2; s++) {
            bf16x8 af[4], bfr[4];
#pragma unroll
            for (int i = 0; i < 4; i++) {
                const int lm = wm * 64 + i * 16 + ln;
                af[i] = *(const bf16x8*)&As[cur][lm * 64 + ((s * 4 + quad) ^ (ln & 7)) * 8];
                const int lnn = wn * 64 + i * 16 + ln;
                bfr[i] = *(const bf16x8*)&Bs[cur][lnn * 64 + ((s * 4 + quad) ^ (ln & 7)) * 8];
            }
#pragma unroll
            for (int i = 0; i < 4; i++)
#pragma unroll
                for (int j = 0; j < 4; j++)
                    acc[i][j] = mfma16(af[i], bfr[j], acc[i][j]);
        }
    }

    if (col0 >= 2 * DM) {   // V region -> transposed bf16 [d][seq]
#pragma unroll
        for (int j = 0; j < 4; j++) {
            const int n = col0 + wn * 64 + j * 16 + ln;
            const float bv = bias[n];
#pragma unroll
            for (int i = 0; i < 4; i++) {
                const int mb = row0 + wm * 64 + i * 16 + quad * 4;
                uint2 pkd;
                pkd.x = pk2(acc[i][j][0] + bv, acc[i][j][1] + bv);
                pkd.y = pk2(acc[i][j][2] + bv, acc[i][j][3] + bv);
                *(uint2*)&vt_out[(size_t)(n - 2 * DM) * SEQ + mb] = pkd;
            }
        }
        return;
    }

#pragma unroll
    for (int j = 0; j < 4; j++) {
        const int n = col0 + wn * 64 + j * 16 + ln;
        const float bv = bias[n] * ((n < DM) ? QSCALE : 1.0f);
#pragma unroll
        for (int i = 0; i < 4; i++) {
            const int mb = row0 + wm * 64 + i * 16 + quad * 4;
#pragma unroll
            for (int r = 0; r < 4; r++)
                Cv[(size_t)(mb + r) * N + n] = f2bf(acc[i][j][r] + bv);
        }
    }
}

// ---------------- split-K MFMA flash attention: 512 threads, 128 q-rows/block ------------
// Grid (144, 8). Slot e = 143-bx: group g covers qt in [4g,4g+4) with g+1 chunks
// each (cumulative 2g(g+1)); chunks are <=8 K-tiles of 64 keys.
__global__ __launch_bounds__(512) void attn_split(const ushort_t* __restrict__ qkv_b,
                                                  const ushort_t* __restrict__ vt,
                                                  ushort_t* __restrict__ po,
                                                  float2* __restrict__ pml) {
    __shared__ __align__(16) ushort_t Ks[2][64 * 64];
    __shared__ __align__(16) ushort_t Vs[2][64 * 64];
    __shared__ __align__(16) ushort_t Ps[128 * 72];

    const int tid  = threadIdx.x;
    const int lane = tid & 63;
    const int w    = tid >> 6;          // 0..7
    const int quad = lane >> 4;
    const int ln   = lane & 15;
    const int h    = blockIdx.y;

    const int e = 143 - (int)blockIdx.x;
    int g = 0;
    while (e >= 2 * (g + 1) * (g + 2)) g++;
    const int off = e - 2 * g * (g + 1);
    const int nc  = g + 1;
    const int qt  = 4 * g + off / nc;
    const int c   = off % nc;
    const int T   = 2 * qt + 2;
    const int jt0 = (c * T) / nc;
    const int jt1 = ((c + 1) * T) / nc;
    const int q0  = qt * 128;

    const ushort_t* qrow = qkv_b + (size_t)(q0 + w * 16 + ln) * TQK + h * DH;
    const bf16x8 a0 = *(const bf16x8*)(qrow + quad * 8);
    const bf16x8 a1 = *(const bf16x8*)(qrow + quad * 8 + 32);

    const short oneb = (short)0x3F80;
    const bf16x8 vone = {oneb, oneb, oneb, oneb, oneb, oneb, oneb, oneb};

    float m_q = -INFINITY;
    floatx4 o[4], ol;
#pragma unroll
    for (int t = 0; t < 4; t++) o[t] = (floatx4){0.f, 0.f, 0.f, 0.f};
    ol = (floatx4){0.f, 0.f, 0.f, 0.f};

    const int srow = lane >> 3;
    const int js   = (lane & 7) ^ srow;

    {   // prologue: stage jt0 into buffer 0 (wave w loads its 8-row group)
        const int k0 = jt0 * 64;
        gload_lds16(qkv_b + (size_t)(k0 + w * 8 + srow) * TQK + DM + h * DH + js * 8,
                    &Ks[0][w * 512]);
        gload_lds16(vt + (size_t)(h * DH + w * 8 + srow) * SEQ + k0 + js * 8,
                    &Vs[0][w * 512]);
    }

    for (int jt = jt0; jt < jt1; ++jt) {
        const int cur = (jt - jt0) & 1;
        const int k0  = jt * 64;
        __syncthreads();
        if (jt + 1 < jt1) {
            const int k0n = (jt + 1) * 64;
            gload_lds16(qkv_b + (size_t)(k0n + w * 8 + srow) * TQK + DM + h * DH + js * 8,
                        &Ks[cur ^ 1][w * 512]);
            gload_lds16(vt + (size_t)(h * DH + w * 8 + srow) * SEQ + k0n + js * 8,
                        &Vs[cur ^ 1][w * 512]);
        }

        // ---- S = Q K^T (pre-scaled, base-2 domain) ----
        floatx4 sa[4];
#pragma unroll
        for (int t = 0; t < 4; t++) {
            const int n = t * 16 + ln;
            const bf16x8 b0 = *(const bf16x8*)&Ks[cur][n * 64 + ((quad) ^ (ln & 7)) * 8];
            const bf16x8 b1 = *(const bf16x8*)&Ks[cur][n * 64 + ((4 + quad) ^ (ln & 7)) * 8];
            floatx4 acc = {0.f, 0.f, 0.f, 0.f};
            acc = mfma16(a0, b0, acc);
            acc = mfma16(a1, b1, acc);
            sa[t] = acc;
        }

        if (k0 + 63 > q0 + w * 16) {   // tile can violate causality for this wave
#pragma unroll
            for (int t = 0; t < 4; t++) {
                const int cg2 = k0 + t * 16 + ln;
#pragma unroll
                for (int r = 0; r < 4; r++) {
                    const int rg = q0 + w * 16 + quad * 4 + r;
                    if (cg2 > rg) sa[t][r] = -INFINITY;
                }
            }
        }

        // ---- online softmax: one shared max per quad; clamp avoids NaN on all-masked ----
        float mx = sa[0][0];
#pragma unroll
        for (int t = 0; t < 4; t++)
#pragma unroll
            for (int r = 0; r < 4; r++) mx = fmaxf(mx, sa[t][r]);
        mx = row_max16(mx);
        const float mn = fmaxf(fmaxf(m_q, mx), -1e30f);
        const float alpha = ex2(m_q - mn);   // 0 on first tile (m_q=-inf)
        m_q = mn;
#pragma unroll
        for (int t = 0; t < 4; t++)
#pragma unroll
            for (int r = 0; r < 4; r++) {
                const float p = ex2(sa[t][r] - mn);
                Ps[(w * 16 + quad * 4 + r) * 72 + t * 16 + ln] =
                    (ushort_t)(__float_as_uint(p) >> 16);
            }
        if (alpha < 1.0f) {
#pragma unroll
            for (int t = 0; t < 4; t++)
#pragma unroll
                for (int r = 0; r < 4; r++) o[t][r] *= alpha;
#pragma unroll
            for (int r = 0; r < 4; r++) ol[r] *= alpha;
        }

        __builtin_amdgcn_wave_barrier();   // order P writes before A-frag reads (same wave)

        const bf16x8 p0 = *(const bf16x8*)&Ps[(w * 16 + ln) * 72 + quad * 8];
        const bf16x8 p1 = *(const bf16x8*)&Ps[(w * 16 + ln) * 72 + quad * 8 + 32];
#pragma unroll
        for (int t = 0; t < 4; t++) {
            const int d = t * 16 + ln;
            const bf16x8 v0 = *(const bf16x8*)&Vs[cur][d * 64 + ((quad) ^ (ln & 7)) * 8];
            const bf16x8 v1 = *(const bf16x8*)&Vs[cur][d * 64 + ((4 + quad) ^ (ln & 7)) * 8];
            o[t] = mfma16(p0, v0, o[t]);
            o[t] = mfma16(p1, v1, o[t]);
        }
        ol = mfma16(p0, vone, ol);
        ol = mfma16(p1, vone, ol);
    }

    // partials: unnormalized bf16 O (128x64) + fp32 (m,l) per row; slot = e
    const size_t pbase  = ((size_t)h * 144 + e) * (128 * 64);
    const size_t mlbase = ((size_t)h * 144 + e) * 128;
#pragma unroll
    for (int t = 0; t < 4; t++)
#pragma unroll
        for (int r = 0; r < 4; r++)
            po[pbase + (size_t)(w * 16 + quad * 4 + r) * 64 + t * 16 + ln] = f2bf(o[t][r]);
    if (ln == 0) {
#pragma unroll
        for (int r = 0; r < 4; r++)
            pml[mlbase + w * 16 + quad * 4 + r] = make_float2(m_q, ol[r]);
    }
}

// ---------------- GEMM2 with fused split-K combine ----------------
// out = attn_out @ W_out^T + b_out. K-step kt consumes exactly head kt's 64
// dims, so head kt's partials are combined directly into the LDS A-tile
// (pitch 72, ds_write) inside the double-buffered K-loop. Grid (4, 32), 512 thr.
__global__ __launch_bounds__(512) void gemm_out(const ushort_t* __restrict__ po,
                                                const float2* __restrict__ pml,
                                                const ushort_t* __restrict__ BT,
                                                const float* __restrict__ bias,
                                                float* __restrict__ out) {
    __shared__ __align__(16) ushort_t As[2][128 * 72];
    __shared__ __align__(16) ushort_t Bs[2][128 * 64];
    const int tid  = threadIdx.x;
    const int lane = tid & 63;
    const int w    = tid >> 6;          // 0..7
    const int quad = lane >> 4;
    const int ln   = lane & 15;
    const int row0 = blockIdx.y * 128;
    const int col0 = blockIdx.x * 128;
    const int wm = w >> 2, wn = w & 3;  // 2x4 wave grid: 64 rows x 32 cols each
    const int srow = lane >> 3;
    const int js   = (lane & 7) ^ srow;

    // split-K slot range for this q-tile (qt = blockIdx.y)
    const int qt = blockIdx.y;
    const int gq = qt >> 2;
    const int nc = gq + 1;
    const int sbase = 2 * gq * (gq + 1) + (qt & 3) * nc;

    const int cr = tid >> 2, cg = tid & 3;   // combine: row 0..127, 16-dim slice

    floatx4 acc[4][2];
#pragma unroll
    for (int i = 0; i < 4; i++)
#pragma unroll
        for (int j = 0; j < 2; j++) acc[i][j] = (floatx4){0.f, 0.f, 0.f, 0.f};

    // ---- combine head `head` partials into As[buf] ----
    auto combine = [&](int head, int buf) {
        float2 ml[8];
        float M = -INFINITY;
        for (int ci = 0; ci < nc; ci++) {
            ml[ci] = pml[((size_t)head * 144 + sbase + ci) * 128 + cr];
            M = fmaxf(M, ml[ci].x);
        }
        float L = 0.f;
        float a[16];
#pragma unroll
        for (int j = 0; j < 16; j++) a[j] = 0.f;
        for (int ci = 0; ci < nc; ci++) {
            const float wgt = ex2(ml[ci].x - M);
            L += wgt * ml[ci].y;
            const ushort_t* p = po + ((size_t)head * 144 + sbase + ci) * (128 * 64)
                                   + (size_t)cr * 64 + cg * 16;
            uint4 u0 = ((const uint4*)p)[0];
            uint4 u1 = ((const uint4*)p)[1];
            const unsigned int uu[8] = {u0.x, u0.y, u0.z, u0.w, u1.x, u1.y, u1.z, u1.w};
#pragma unroll
            for (int j = 0; j < 8; j++) {
                a[2 * j]     += wgt * bflo(uu[j]);
                a[2 * j + 1] += wgt * bfhi(uu[j]);
            }
        }
        const float inv = 1.0f / L;
        unsigned int pk[8];
#pragma unroll
        for (int j = 0; j < 8; j++)
            pk[j] = pk2(a[2 * j] * inv, a[2 * j + 1] * inv);
        uint4* dst = (uint4*)&As[buf][cr * 72 + cg * 16];
        dst[0] = make_uint4(pk[0], pk[1], pk[2], pk[3]);
        dst[1] = make_uint4(pk[4], pk[5], pk[6], pk[7]);
    };
    auto loadB = [&](int kt, int buf) {
#pragma unroll
        for (int i = 0; i < 2; i++) {
            const int cgrp = w * 2 + i;   // 0..15 8-row groups of the 128 BT rows
            gload_lds16(BT + (size_t)(col0 + cgrp * 8 + srow) * DM + kt * 64 + js * 8,
                        &Bs[buf][cgrp * 512]);
        }
    };

    loadB(0, 0);
    combine(0, 0);

    for (int kt = 0; kt < 8; kt++) {
        const int cur = kt & 1;
        __syncthreads();   // drains Bs[cur] gloads + As[cur] ds_writes
        if (kt < 7) {
            loadB(kt + 1, cur ^ 1);
            combine(kt + 1, cur ^ 1);
        }
#pragma unroll
        for (int s = 0; s < 2; s++) {
            bf16x8 af[4], bfr[2];
#pragma unroll
            for (int i = 0; i < 4; i++) {
                const int lm = wm * 64 + i * 16 + ln;
                af[i] = *(const bf16x8*)&As[cur][lm * 72 + (s * 4 + quad) * 8];
            }
#pragma unroll
            for (int j = 0; j < 2; j++) {
                const int lnn = wn * 32 + j * 16 + ln;
                bfr[j] = *(const bf16x8*)&Bs[cur][lnn * 64 + ((s * 4 + quad) ^ (ln & 7)) * 8];
            }
#pragma unroll
            for (int i = 0; i < 4; i++)
#pragma unroll
                for (int j = 0; j < 2; j++)
                    acc[i][j] = mfma16(af[i], bfr[j], acc[i][j]);
        }
    }

#pragma unroll
    for (int j = 0; j < 2; j++) {
        const int n = col0 + wn * 32 + j * 16 + ln;
        const float bv = bias[n];
#pragma unroll
        for (int i = 0; i < 4; i++) {
            const int mb = row0 + wm * 64 + i * 16 + quad * 4;
#pragma unroll
            for (int r = 0; r < 4; r++)
                out[(size_t)(mb + r) * DM + n] = acc[i][j][r] + bv;
        }
    }
}

extern "C" void kernel_launch(void* const* d_in, const int* in_sizes, int n_in,
                              void* d_out, int out_size, void* d_ws, size_t ws_size,
                              hipStream_t stream) {
    const float* x     = (const float*)d_in[0];
    const float* W_in  = (const float*)d_in[1];
    const float* b_in  = (const float*)d_in[2];
    const float* W_out = (const float*)d_in[3];
    const float* b_out = (const float*)d_in[4];
    float* out = (float*)d_out;

    char* ws = (char*)d_ws;
    ushort_t* xb    = (ushort_t*)ws;                    //  4 MB   x bf16 [4096][512]
    ushort_t* wti   = (ushort_t*)(ws + (4u  << 20));    //  1.5 MB W_in^T bf16 (Q cols x QSCALE)
    ushort_t* wto   = (ushort_t*)(ws + (6u  << 20));    //  0.5 MB W_out^T bf16
    ushort_t* qkv_b = (ushort_t*)(ws + (7u  << 20));    // 12 MB   qkv bf16 (V third unused)
    ushort_t* vtb   = (ushort_t*)(ws + (19u << 20));    //  4 MB   V^T bf16 [512][4096]
    ushort_t* po    = (ushort_t*)(ws + (23u << 20));    // 18.9 MB partial O bf16 [8][144][128*64]
    float2*   pml   = (float2*)  (ws + (42u << 20));    //  1.2 MB partial (m,l) [8][144][128]

    // 0) fused prep: x->bf16 | W_in^T | W_out^T
    prep<<<1280, 256, 0, stream>>>(x, W_in, W_out, xb, wti, wto);

    // 1) qkv = x @ W_in + b_in; Q pre-scaled; V diverted transposed to vtb
    gemm_in<<<dim3(TQK / 128, SEQ / 128), 256, 0, stream>>>(xb, wti, b_in, qkv_b, vtb);

    // 2) split-K causal flash attention -> partials (512-thread blocks)
    attn_split<<<dim3(144, NH), 512, 0, stream>>>(qkv_b, vtb, po, pml);

    // 3) out = combine(po) @ W_out + b_out (combine fused into K-loop)
    gemm_out<<<dim3(DM / 128, SEQ / 128), 512, 0, stream>>>(po, pml, wto, b_out, out);
}

// Round 7
// 154.684 us; speedup vs baseline: 14.0182x; 1.1211x over previous
//
#include <hip/hip_runtime.h>
#include <math.h>

#define SEQ 4096
#define DM 512
#define NH 8
#define DH 64
#define TQK (3 * DM)   // 1536
#define QSCALE 0.18033688011112042f   // log2(e)/8 : folds softmax scale + base-2 exp

typedef __attribute__((ext_vector_type(8))) short bf16x8;
typedef __attribute__((ext_vector_type(4))) float floatx4;
typedef unsigned short ushort_t;

__device__ __forceinline__ floatx4 mfma16(bf16x8 a, bf16x8 b, floatx4 c) {
    return __builtin_amdgcn_mfma_f32_16x16x32_bf16(a, b, c, 0, 0, 0);
}
__device__ __forceinline__ float ex2(float x) { return __builtin_amdgcn_exp2f(x); }

__device__ __forceinline__ unsigned int pk2(float a, float b) {
    unsigned int ua = __float_as_uint(a); ua = (ua + 0x7FFFu + ((ua >> 16) & 1u)) >> 16;
    unsigned int ub = __float_as_uint(b); ub = (ub + 0x7FFFu + ((ub >> 16) & 1u)) >> 16;
    return ua | (ub << 16);
}
__device__ __forceinline__ unsigned short f2bf(float x) {
    unsigned int u = __float_as_uint(x);
    return (unsigned short)((u + 0x7FFFu + ((u >> 16) & 1u)) >> 16);
}
__device__ __forceinline__ float bflo(unsigned int u) { return __uint_as_float(u << 16); }
__device__ __forceinline__ float bfhi(unsigned int u) { return __uint_as_float(u & 0xFFFF0000u); }

__device__ __forceinline__ void gload_lds16(const void* g, void* l) {
    __builtin_amdgcn_global_load_lds(
        (const __attribute__((address_space(1))) unsigned int*)g,
        (__attribute__((address_space(3))) unsigned int*)l, 16, 0, 0);
}

#define DPPMAX(x, ctrl) \
    (x) = fmaxf((x), __int_as_float(__builtin_amdgcn_update_dpp(0, __float_as_int(x), (ctrl), 0xF, 0xF, true)))
__device__ __forceinline__ float row_max16(float x) {
    DPPMAX(x, 0xB1);   // quad_perm xor1
    DPPMAX(x, 0x4E);   // quad_perm xor2
    DPPMAX(x, 0x141);  // row_half_mirror
    DPPMAX(x, 0x140);  // row_mirror
    return x;
}

// ---------------- fused prep: x->bf16, W_in^T (Q cols pre-scaled), W_out^T ----------------
__global__ __launch_bounds__(256) void prep(const float* __restrict__ x,
                                            const float* __restrict__ W_in,
                                            const float* __restrict__ W_out,
                                            ushort_t* __restrict__ xb,
                                            ushort_t* __restrict__ wti,
                                            ushort_t* __restrict__ wto) {
    __shared__ float T[64][65];
    const int bid = blockIdx.x, tid = threadIdx.x;
    if (bid < 1024) {
        const int i = bid * 256 + tid;
        const float4* p = (const float4*)x + (size_t)i * 2;
        float4 f0 = p[0], f1 = p[1];
        ((uint4*)xb)[i] = make_uint4(pk2(f0.x, f0.y), pk2(f0.z, f0.w),
                                     pk2(f1.x, f1.y), pk2(f1.z, f1.w));
        return;
    }
    const float* W; ushort_t* WT; int N, K, n0, k0; bool qscale;
    if (bid < 1216) { int id = bid - 1024; W = W_in;  WT = wti; N = TQK; K = DM;
                      n0 = (id % 24) * 64; k0 = (id / 24) * 64; qscale = true; }
    else            { int id = bid - 1216; W = W_out; WT = wto; N = DM;  K = DM;
                      n0 = (id % 8) * 64;  k0 = (id / 8) * 64;  qscale = false; }
    {
        const int r = tid >> 2, g = tid & 3;
        const float* src = W + (size_t)(k0 + r) * N + n0 + g * 16;
#pragma unroll
        for (int i = 0; i < 4; i++) {
            float4 f = ((const float4*)src)[i];
            T[g * 16 + i * 4 + 0][r] = f.x;
            T[g * 16 + i * 4 + 1][r] = f.y;
            T[g * 16 + i * 4 + 2][r] = f.z;
            T[g * 16 + i * 4 + 3][r] = f.w;
        }
    }
    __syncthreads();
    const int nr = tid >> 2, g2 = tid & 3;
    const float sc = (qscale && (n0 + nr < DM)) ? QSCALE : 1.0f;
    unsigned int pk[8];
#pragma unroll
    for (int j = 0; j < 8; j++)
        pk[j] = pk2(T[nr][g2 * 16 + 2 * j] * sc, T[nr][g2 * 16 + 2 * j + 1] * sc);
    ushort_t* dst = WT + (size_t)(n0 + nr) * K + k0 + g2 * 16;
    ((uint4*)dst)[0] = make_uint4(pk[0], pk[1], pk[2], pk[3]);
    ((uint4*)dst)[1] = make_uint4(pk[4], pk[5], pk[6], pk[7]);
}

// ---------------- GEMM1: qkv = x @ W_in^T + b_in (bf16 out, V diverted transposed) -------
__global__ __launch_bounds__(256) void gemm_in(const ushort_t* __restrict__ A,
                                               const ushort_t* __restrict__ BT,
                                               const float* __restrict__ bias,
                                               ushort_t* __restrict__ Cv,
                                               ushort_t* __restrict__ vt_out) {
    __shared__ __align__(16) ushort_t As[2][128 * 64];
    __shared__ __align__(16) ushort_t Bs[2][128 * 64];
    const int tid  = threadIdx.x;
    const int lane = tid & 63;
    const int w    = tid >> 6;
    const int quad = lane >> 4;
    const int ln   = lane & 15;
    const int row0 = blockIdx.y * 128;
    const int col0 = blockIdx.x * 128;
    const int wm = w >> 1, wn = w & 1;
    const int srow = lane >> 3;
    const int js   = (lane & 7) ^ srow;
    const int K = DM, N = TQK;

    floatx4 acc[4][4];
#pragma unroll
    for (int i = 0; i < 4; i++)
#pragma unroll
        for (int j = 0; j < 4; j++) acc[i][j] = (floatx4){0.f, 0.f, 0.f, 0.f};

#pragma unroll
    for (int i = 0; i < 4; i++) {
        const int c = w * 4 + i;
        gload_lds16(A  + (size_t)(row0 + c * 8 + srow) * K + js * 8, &As[0][c * 512]);
        gload_lds16(BT + (size_t)(col0 + c * 8 + srow) * K + js * 8, &Bs[0][c * 512]);
    }

    for (int kt = 0; kt < 8; kt++) {
        const int cur = kt & 1;
        __syncthreads();
        if (kt < 7) {
            const int k0n = (kt + 1) << 6;
#pragma unroll
            for (int i = 0; i < 4; i++) {
                const int c = w * 4 + i;
                gload_lds16(A  + (size_t)(row0 + c * 8 + srow) * K + k0n + js * 8, &As[cur ^ 1][c * 512]);
                gload_lds16(BT + (size_t)(col0 + c * 8 + srow) * K + k0n + js * 8, &Bs[cur ^ 1][c * 512]);
            }
        }
#pragma unroll
        for (int s = 0; s < 2; s++) {
            bf16x8 af[4], bfr[4];
#pragma unroll
            for (int i = 0; i < 4; i++) {
                const int lm = wm * 64 + i * 16 + ln;
                af[i] = *(const bf16x8*)&As[cur][lm * 64 + ((s * 4 + quad) ^ (ln & 7)) * 8];
                const int lnn = wn * 64 + i * 16 + ln;
                bfr[i] = *(const bf16x8*)&Bs[cur][lnn * 64 + ((s * 4 + quad) ^ (ln & 7)) * 8];
            }
#pragma unroll
            for (int i = 0; i < 4; i++)
#pragma unroll
                for (int j = 0; j < 4; j++)
                    acc[i][j] = mfma16(af[i], bfr[j], acc[i][j]);
        }
    }

    if (col0 >= 2 * DM) {   // V region -> transposed bf16 [d][seq]
#pragma unroll
        for (int j = 0; j < 4; j++) {
            const int n = col0 + wn * 64 + j * 16 + ln;
            const float bv = bias[n];
#pragma unroll
            for (int i = 0; i < 4; i++) {
                const int mb = row0 + wm * 64 + i * 16 + quad * 4;
                uint2 pkd;
                pkd.x = pk2(acc[i][j][0] + bv, acc[i][j][1] + bv);
                pkd.y = pk2(acc[i][j][2] + bv, acc[i][j][3] + bv);
                *(uint2*)&vt_out[(size_t)(n - 2 * DM) * SEQ + mb] = pkd;
            }
        }
        return;
    }

#pragma unroll
    for (int j = 0; j < 4; j++) {
        const int n = col0 + wn * 64 + j * 16 + ln;
        const float bv = bias[n] * ((n < DM) ? QSCALE : 1.0f);
#pragma unroll
        for (int i = 0; i < 4; i++) {
            const int mb = row0 + wm * 64 + i * 16 + quad * 4;
#pragma unroll
            for (int r = 0; r < 4; r++)
                Cv[(size_t)(mb + r) * N + n] = f2bf(acc[i][j][r] + bv);
        }
    }
}

// ---------------- split-K MFMA flash attention: 512 threads, 128 q-rows/block ------------
__global__ __launch_bounds__(512) void attn_split(const ushort_t* __restrict__ qkv_b,
                                                  const ushort_t* __restrict__ vt,
                                                  ushort_t* __restrict__ po,
                                                  float2* __restrict__ pml) {
    __shared__ __align__(16) ushort_t Ks[2][64 * 64];
    __shared__ __align__(16) ushort_t Vs[2][64 * 64];
    __shared__ __align__(16) ushort_t Ps[128 * 72];

    const int tid  = threadIdx.x;
    const int lane = tid & 63;
    const int w    = tid >> 6;
    const int quad = lane >> 4;
    const int ln   = lane & 15;
    const int h    = blockIdx.y;

    const int e = 143 - (int)blockIdx.x;
    int g = 0;
    while (e >= 2 * (g + 1) * (g + 2)) g++;
    const int off = e - 2 * g * (g + 1);
    const int nc  = g + 1;
    const int qt  = 4 * g + off / nc;
    const int c   = off % nc;
    const int T   = 2 * qt + 2;
    const int jt0 = (c * T) / nc;
    const int jt1 = ((c + 1) * T) / nc;
    const int q0  = qt * 128;

    const ushort_t* qrow = qkv_b + (size_t)(q0 + w * 16 + ln) * TQK + h * DH;
    const bf16x8 a0 = *(const bf16x8*)(qrow + quad * 8);
    const bf16x8 a1 = *(const bf16x8*)(qrow + quad * 8 + 32);

    const short oneb = (short)0x3F80;
    const bf16x8 vone = {oneb, oneb, oneb, oneb, oneb, oneb, oneb, oneb};

    float m_q = -INFINITY;
    floatx4 o[4], ol;
#pragma unroll
    for (int t = 0; t < 4; t++) o[t] = (floatx4){0.f, 0.f, 0.f, 0.f};
    ol = (floatx4){0.f, 0.f, 0.f, 0.f};

    const int srow = lane >> 3;
    const int js   = (lane & 7) ^ srow;

    {   // prologue: stage jt0 into buffer 0 (wave w loads its 8-row group)
        const int k0 = jt0 * 64;
        gload_lds16(qkv_b + (size_t)(k0 + w * 8 + srow) * TQK + DM + h * DH + js * 8,
                    &Ks[0][w * 512]);
        gload_lds16(vt + (size_t)(h * DH + w * 8 + srow) * SEQ + k0 + js * 8,
                    &Vs[0][w * 512]);
    }

    for (int jt = jt0; jt < jt1; ++jt) {
        const int cur = (jt - jt0) & 1;
        const int k0  = jt * 64;
        __syncthreads();
        if (jt + 1 < jt1) {
            const int k0n = (jt + 1) * 64;
            gload_lds16(qkv_b + (size_t)(k0n + w * 8 + srow) * TQK + DM + h * DH + js * 8,
                        &Ks[cur ^ 1][w * 512]);
            gload_lds16(vt + (size_t)(h * DH + w * 8 + srow) * SEQ + k0n + js * 8,
                        &Vs[cur ^ 1][w * 512]);
        }

        floatx4 sa[4];
#pragma unroll
        for (int t = 0; t < 4; t++) {
            const int n = t * 16 + ln;
            const bf16x8 b0 = *(const bf16x8*)&Ks[cur][n * 64 + ((quad) ^ (ln & 7)) * 8];
            const bf16x8 b1 = *(const bf16x8*)&Ks[cur][n * 64 + ((4 + quad) ^ (ln & 7)) * 8];
            floatx4 acc = {0.f, 0.f, 0.f, 0.f};
            acc = mfma16(a0, b0, acc);
            acc = mfma16(a1, b1, acc);
            sa[t] = acc;
        }

        if (k0 + 63 > q0 + w * 16) {
#pragma unroll
            for (int t = 0; t < 4; t++) {
                const int cg2 = k0 + t * 16 + ln;
#pragma unroll
                for (int r = 0; r < 4; r++) {
                    const int rg = q0 + w * 16 + quad * 4 + r;
                    if (cg2 > rg) sa[t][r] = -INFINITY;
                }
            }
        }

        float mx = sa[0][0];
#pragma unroll
        for (int t = 0; t < 4; t++)
#pragma unroll
            for (int r = 0; r < 4; r++) mx = fmaxf(mx, sa[t][r]);
        mx = row_max16(mx);
        const float mn = fmaxf(fmaxf(m_q, mx), -1e30f);
        const float alpha = ex2(m_q - mn);
        m_q = mn;
#pragma unroll
        for (int t = 0; t < 4; t++)
#pragma unroll
            for (int r = 0; r < 4; r++) {
                const float p = ex2(sa[t][r] - mn);
                Ps[(w * 16 + quad * 4 + r) * 72 + t * 16 + ln] =
                    (ushort_t)(__float_as_uint(p) >> 16);
            }
        if (alpha < 1.0f) {
#pragma unroll
            for (int t = 0; t < 4; t++)
#pragma unroll
                for (int r = 0; r < 4; r++) o[t][r] *= alpha;
#pragma unroll
            for (int r = 0; r < 4; r++) ol[r] *= alpha;
        }

        __builtin_amdgcn_wave_barrier();

        const bf16x8 p0 = *(const bf16x8*)&Ps[(w * 16 + ln) * 72 + quad * 8];
        const bf16x8 p1 = *(const bf16x8*)&Ps[(w * 16 + ln) * 72 + quad * 8 + 32];
#pragma unroll
        for (int t = 0; t < 4; t++) {
            const int d = t * 16 + ln;
            const bf16x8 v0 = *(const bf16x8*)&Vs[cur][d * 64 + ((quad) ^ (ln & 7)) * 8];
            const bf16x8 v1 = *(const bf16x8*)&Vs[cur][d * 64 + ((4 + quad) ^ (ln & 7)) * 8];
            o[t] = mfma16(p0, v0, o[t]);
            o[t] = mfma16(p1, v1, o[t]);
        }
        ol = mfma16(p0, vone, ol);
        ol = mfma16(p1, vone, ol);
    }

    const size_t pbase  = ((size_t)h * 144 + e) * (128 * 64);
    const size_t mlbase = ((size_t)h * 144 + e) * 128;
#pragma unroll
    for (int t = 0; t < 4; t++)
#pragma unroll
        for (int r = 0; r < 4; r++)
            po[pbase + (size_t)(w * 16 + quad * 4 + r) * 64 + t * 16 + ln] = f2bf(o[t][r]);
    if (ln == 0) {
#pragma unroll
        for (int r = 0; r < 4; r++)
            pml[mlbase + w * 16 + quad * 4 + r] = make_float2(m_q, ol[r]);
    }
}

// ---------------- combine partials -> attn_out bf16 [SEQ][DM] ----------------
// Grid (32, 8) x 512 threads: block = one (h, 128-row q-tile). Thread: row =
// tid>>2 (128), g = tid&3 (16-dim slice). All partial loads are independent.
__global__ __launch_bounds__(512) void attn_combine(const ushort_t* __restrict__ po,
                                                    const float2* __restrict__ pml,
                                                    ushort_t* __restrict__ aob) {
    const int qt = blockIdx.x, h = blockIdx.y;
    const int gq = qt >> 2;
    const int nc = gq + 1;
    const int sbase = 2 * gq * (gq + 1) + (qt & 3) * nc;
    const int row = threadIdx.x >> 2, g = threadIdx.x & 3;

    float2 ml[8];
    float M = -INFINITY;
    for (int ci = 0; ci < nc; ci++) {
        ml[ci] = pml[((size_t)h * 144 + sbase + ci) * 128 + row];
        M = fmaxf(M, ml[ci].x);
    }
    float L = 0.f;
    float acc[16];
#pragma unroll
    for (int j = 0; j < 16; j++) acc[j] = 0.f;

    for (int ci = 0; ci < nc; ci++) {
        const float wgt = ex2(ml[ci].x - M);
        L += wgt * ml[ci].y;
        const ushort_t* p = po + ((size_t)h * 144 + sbase + ci) * (128 * 64)
                               + (size_t)row * 64 + g * 16;
        uint4 u0 = ((const uint4*)p)[0];
        uint4 u1 = ((const uint4*)p)[1];
        const unsigned int uu[8] = {u0.x, u0.y, u0.z, u0.w, u1.x, u1.y, u1.z, u1.w};
#pragma unroll
        for (int j = 0; j < 8; j++) {
            acc[2 * j]     += wgt * bflo(uu[j]);
            acc[2 * j + 1] += wgt * bfhi(uu[j]);
        }
    }
    const float inv = 1.0f / L;
    unsigned int pk[8];
#pragma unroll
    for (int j = 0; j < 8; j++)
        pk[j] = pk2(acc[2 * j] * inv, acc[2 * j + 1] * inv);
    ushort_t* dst = aob + (size_t)(qt * 128 + row) * DM + h * DH + g * 16;
    ((uint4*)dst)[0] = make_uint4(pk[0], pk[1], pk[2], pk[3]);
    ((uint4*)dst)[1] = make_uint4(pk[4], pk[5], pk[6], pk[7]);
}

// ---------------- GEMM2: out = aob @ W_out^T + b_out (fp32), 128x64 tiles ----------------
__global__ __launch_bounds__(256) void gemm_out(const ushort_t* __restrict__ A,
                                                const ushort_t* __restrict__ BT,
                                                const float* __restrict__ bias,
                                                float* __restrict__ out) {
    __shared__ __align__(16) ushort_t As[2][128 * 64];
    __shared__ __align__(16) ushort_t Bs[2][64 * 64];
    const int tid  = threadIdx.x;
    const int lane = tid & 63;
    const int w    = tid >> 6;
    const int quad = lane >> 4;
    const int ln   = lane & 15;
    const int row0 = blockIdx.y * 128;
    const int col0 = blockIdx.x * 64;
    const int wm = w >> 1, wn = w & 1;   // 2x2 wave grid: 64 rows x 32 cols each
    const int srow = lane >> 3;
    const int js   = (lane & 7) ^ srow;

    floatx4 acc[4][2];
#pragma unroll
    for (int i = 0; i < 4; i++)
#pragma unroll
        for (int j = 0; j < 2; j++) acc[i][j] = (floatx4){0.f, 0.f, 0.f, 0.f};

#pragma unroll
    for (int i = 0; i < 4; i++) {
        const int c = w * 4 + i;
        gload_lds16(A + (size_t)(row0 + c * 8 + srow) * DM + js * 8, &As[0][c * 512]);
    }
#pragma unroll
    for (int i = 0; i < 2; i++) {
        const int c = w * 2 + i;
        gload_lds16(BT + (size_t)(col0 + c * 8 + srow) * DM + js * 8, &Bs[0][c * 512]);
    }

    for (int kt = 0; kt < 8; kt++) {
        const int cur = kt & 1;
        __syncthreads();
        if (kt < 7) {
            const int k0n = (kt + 1) << 6;
#pragma unroll
            for (int i = 0; i < 4; i++) {
                const int c = w * 4 + i;
                gload_lds16(A + (size_t)(row0 + c * 8 + srow) * DM + k0n + js * 8, &As[cur ^ 1][c * 512]);
            }
#pragma unroll
            for (int i = 0; i < 2; i++) {
                const int c = w * 2 + i;
                gload_lds16(BT + (size_t)(col0 + c * 8 + srow) * DM + k0n + js * 8, &Bs[cur ^ 1][c * 512]);
            }
        }
#pragma unroll
        for (int s = 0; s < 2; s++) {
            bf16x8 af[4], bfr[2];
#pragma unroll
            for (int i = 0; i < 4; i++) {
                const int lm = wm * 64 + i * 16 + ln;
                af[i] = *(const bf16x8*)&As[cur][lm * 64 + ((s * 4 + quad) ^ (ln & 7)) * 8];
            }
#pragma unroll
            for (int j = 0; j < 2; j++) {
                const int lnn = wn * 32 + j * 16 + ln;
                bfr[j] = *(const bf16x8*)&Bs[cur][lnn * 64 + ((s * 4 + quad) ^ (ln & 7)) * 8];
            }
#pragma unroll
            for (int i = 0; i < 4; i++)
#pragma unroll
                for (int j = 0; j < 2; j++)
                    acc[i][j] = mfma16(af[i], bfr[j], acc[i][j]);
        }
    }

#pragma unroll
    for (int j = 0; j < 2; j++) {
        const int n = col0 + wn * 32 + j * 16 + ln;
        const float bv = bias[n];
#pragma unroll
        for (int i = 0; i < 4; i++) {
            const int mb = row0 + wm * 64 + i * 16 + quad * 4;
#pragma unroll
            for (int r = 0; r < 4; r++)
                out[(size_t)(mb + r) * DM + n] = acc[i][j][r] + bv;
        }
    }
}

extern "C" void kernel_launch(void* const* d_in, const int* in_sizes, int n_in,
                              void* d_out, int out_size, void* d_ws, size_t ws_size,
                              hipStream_t stream) {
    const float* x     = (const float*)d_in[0];
    const float* W_in  = (const float*)d_in[1];
    const float* b_in  = (const float*)d_in[2];
    const float* W_out = (const float*)d_in[3];
    const float* b_out = (const float*)d_in[4];
    float* out = (float*)d_out;

    char* ws = (char*)d_ws;
    ushort_t* xb    = (ushort_t*)ws;                    //  4 MB   x bf16 [4096][512]
    ushort_t* wti   = (ushort_t*)(ws + (4u  << 20));    //  1.5 MB W_in^T bf16 (Q cols x QSCALE)
    ushort_t* wto   = (ushort_t*)(ws + (6u  << 20));    //  0.5 MB W_out^T bf16
    ushort_t* qkv_b = (ushort_t*)(ws + (7u  << 20));    // 12 MB   qkv bf16 (V third unused)
    ushort_t* vtb   = (ushort_t*)(ws + (19u << 20));    //  4 MB   V^T bf16 [512][4096]
    ushort_t* po    = (ushort_t*)(ws + (23u << 20));    // 18.9 MB partial O bf16 [8][144][128*64]
    float2*   pml   = (float2*)  (ws + (42u << 20));    //  1.2 MB partial (m,l) [8][144][128]
    ushort_t* aob   = (ushort_t*)(ws + (44u << 20));    //  4 MB   attn out bf16 [4096][512]

    // 0) fused prep: x->bf16 | W_in^T | W_out^T
    prep<<<1280, 256, 0, stream>>>(x, W_in, W_out, xb, wti, wto);

    // 1) qkv = x @ W_in + b_in; Q pre-scaled; V diverted transposed to vtb
    gemm_in<<<dim3(TQK / 128, SEQ / 128), 256, 0, stream>>>(xb, wti, b_in, qkv_b, vtb);

    // 2) split-K causal flash attention -> partials (512-thread blocks)
    attn_split<<<dim3(144, NH), 512, 0, stream>>>(qkv_b, vtb, po, pml);

    // 3) merge partials -> aob
    attn_combine<<<dim3(SEQ / 128, NH), 512, 0, stream>>>(po, pml, aob);

    // 4) out = aob @ W_out + b_out (fp32)
    gemm_out<<<dim3(DM / 64, SEQ / 128), 256, 0, stream>>>(aob, wto, b_out, out);
}